// Round 20
// baseline (388.056 us; speedup 1.0000x reference)
//
#include <hip/hip_runtime.h>

// DGCNN forward. R2: parallel stats. R3: spill-free knn2 selection.
// R4: knn1 8 lanes/query. R5: heads re-parallelized. R6: lin1 bf16 MFMA.
// R7: ec2 PLAIN bf16 FAILED. R8: revert+j-split. R9: ec2 2pts/thread.
// R10: ec2 split-bf16 MFMA. R11: knn2 split-MFMA. R12: fragment-order W.
// R13: ec2 staging vectorized. R14: knn2 hi/lo hoist + scan-order insert.
// R15: lin1 8ct x 4 row-frags. R16: x2 BN'd once. R17: ec2 8pts/block.
// R18: ec2 block-level stats on aliased LDS. R19 LESSON: knn2 occupancy
// was GRID-limited (1024 blocks = 4/CU), not LDS-limited. R20: j-scan
// split into QUARTERS -> grid 2048, 8 blocks/CU now reachable (LDS
// 18.4KB + VGPR<=64 kept); 4-way full-lex merge (exact stable top-k).

#define NB 32
#define NP 1024
#define NPT 32768       // NB*NP
#define KNN 5
#define NE 163840       // NPT*KNN

#define FINF 3.402823466e+38f

typedef __attribute__((ext_vector_type(8))) short bf16x8;
typedef __attribute__((ext_vector_type(4))) float f32x4;

__device__ __forceinline__ bool lex_less(float da, int ja, float db, int jb) {
  return (da < db) || (da == db && ja < jb);
}

__device__ __forceinline__ float f4c(const float4& v, int q) {
  return q == 0 ? v.x : (q == 1 ? v.y : (q == 2 ? v.z : v.w));
}

// f32 -> bf16 (round-to-nearest-even)
__device__ __forceinline__ ushort f2bf(float f) {
  union { float f; unsigned u; } v; v.f = f;
  unsigned r = (v.u + 0x7FFFu + ((v.u >> 16) & 1u)) >> 16;
  return (ushort)r;
}
__device__ __forceinline__ float bf2f(ushort h) {
  union { unsigned u; float f; } v; v.u = ((unsigned)h) << 16;
  return v.f;
}

// insert (dd,jj) into sorted-ascending 5-list, FULL lex (for merges)
__device__ __forceinline__ void insert5(float& d0, float& d1, float& d2, float& d3, float& d4,
                                        int& j0, int& j1, int& j2, int& j3, int& j4,
                                        float dd, int jj) {
  if (lex_less(dd, jj, d4, j4)) {
    bool L0 = lex_less(dd,jj,d0,j0), L1 = lex_less(dd,jj,d1,j1),
         L2 = lex_less(dd,jj,d2,j2), L3 = lex_less(dd,jj,d3,j3);
    d4 = L3 ? d3 : dd;              j4 = L3 ? j3 : jj;
    d3 = L3 ? (L2 ? d2 : dd) : d3;  j3 = L3 ? (L2 ? j2 : jj) : j3;
    d2 = L2 ? (L1 ? d1 : dd) : d2;  j2 = L2 ? (L1 ? j1 : jj) : j2;
    d1 = L1 ? (L0 ? d0 : dd) : d1;  j1 = L1 ? (L0 ? j0 : jj) : j1;
    d0 = L0 ? dd : d0;              j0 = L0 ? jj : j0;
  }
}

// scan-order insert: jj strictly greater than all listed ji -> plain <
__device__ __forceinline__ void insert5f(float& d0, float& d1, float& d2, float& d3, float& d4,
                                         int& j0, int& j1, int& j2, int& j3, int& j4,
                                         float dd, int jj) {
  if (dd < d4) {
    bool L0 = dd < d0, L1 = dd < d1, L2 = dd < d2, L3 = dd < d3;
    d4 = L3 ? d3 : dd;              j4 = L3 ? j3 : jj;
    d3 = L3 ? (L2 ? d2 : dd) : d3;  j3 = L3 ? (L2 ? j2 : jj) : j3;
    d2 = L2 ? (L1 ? d1 : dd) : d2;  j2 = L2 ? (L1 ? j1 : jj) : j2;
    d1 = L1 ? (L0 ? d0 : dd) : d1;  j1 = L1 ? (L0 ? j0 : jj) : j1;
    d0 = L0 ? dd : d0;              j0 = L0 ? jj : j0;
  }
}

// ---------------------------------------------------------------- knn (3-d)
__global__ __launch_bounds__(256) void knn1_kernel(const float* __restrict__ pos,
                                                   int* __restrict__ knn_idx) {
  __shared__ float4 xs4[NP];    // (x, y, z, |x|^2)
  const int b = blockIdx.x >> 5;
  const int seg = blockIdx.x & 31;
  const int t = threadIdx.x;
  for (int i = t; i < NP; i += 256) {
    float x0 = pos[(size_t)b*NP*3 + i*3 + 0];
    float x1 = pos[(size_t)b*NP*3 + i*3 + 1];
    float x2 = pos[(size_t)b*NP*3 + i*3 + 2];
    float sq = __fadd_rn(__fadd_rn(__fmul_rn(x0,x0), __fmul_rn(x1,x1)), __fmul_rn(x2,x2));
    xs4[i] = make_float4(x0, x1, x2, sq);
  }
  __syncthreads();
  const int q = t >> 3;
  const int ql = t & 7;
  const int i = seg * 32 + q;
  const float4 xi = xs4[i];
  const float sqi = xi.w;
  float d0=FINF,d1=FINF,d2=FINF,d3=FINF,d4=FINF;
  int j0=0x7fffffff,j1=0x7fffffff,j2=0x7fffffff,j3=0x7fffffff,j4=0x7fffffff;
  for (int jj = 0; jj < NP/8; ++jj) {
    const int j = jj*8 + ql;    // ascending within lane -> insert5f exact
    float4 v = xs4[j];
    float dot = __fadd_rn(__fadd_rn(__fmul_rn(xi.x,v.x), __fmul_rn(xi.y,v.y)), __fmul_rn(xi.z,v.z));
    float dd = __fsub_rn(__fadd_rn(sqi, v.w), __fmul_rn(2.0f, dot));
    insert5f(d0,d1,d2,d3,d4, j0,j1,j2,j3,j4, dd, j);
  }
  #pragma unroll
  for (int m = 1; m <= 4; m <<= 1) {
    float e0 = __shfl_xor(d0, m, 8), e1 = __shfl_xor(d1, m, 8),
          e2 = __shfl_xor(d2, m, 8), e3 = __shfl_xor(d3, m, 8),
          e4 = __shfl_xor(d4, m, 8);
    int   k0 = __shfl_xor(j0, m, 8), k1 = __shfl_xor(j1, m, 8),
          k2 = __shfl_xor(j2, m, 8), k3 = __shfl_xor(j3, m, 8),
          k4 = __shfl_xor(j4, m, 8);
    insert5(d0,d1,d2,d3,d4, j0,j1,j2,j3,j4, e0, k0);
    insert5(d0,d1,d2,d3,d4, j0,j1,j2,j3,j4, e1, k1);
    insert5(d0,d1,d2,d3,d4, j0,j1,j2,j3,j4, e2, k2);
    insert5(d0,d1,d2,d3,d4, j0,j1,j2,j3,j4, e3, k3);
    insert5(d0,d1,d2,d3,d4, j0,j1,j2,j3,j4, e4, k4);
  }
  if (ql == 0) {
    const size_t row = (size_t)b * NP + i;
    knn_idx[row*KNN+0] = b*NP + j0;
    knn_idx[row*KNN+1] = b*NP + j1;
    knn_idx[row*KNN+2] = b*NP + j2;
    knn_idx[row*KNN+3] = b*NP + j3;
    knn_idx[row*KNN+4] = b*NP + j4;
  }
}

// ------------------------------------------- EdgeConv1 layer1 (6 -> 64) + stats
__global__ __launch_bounds__(256) void ec1_l1_kernel(const float* __restrict__ pos,
    const int* __restrict__ knn_idx, const float* __restrict__ W,
    const float* __restrict__ bias, float* __restrict__ hout,
    double* __restrict__ psum, double* __restrict__ psq) {
  __shared__ float ef[64][6];
  __shared__ float Wl[6][64];
  __shared__ float bl[64];
  __shared__ double red[256];
  const int blk = blockIdx.x, t = threadIdx.x;
  const int ebase = blk * 64;
  if (t < 64) {
    int e = ebase + t;
    int ip = e / KNN;
    int jp = knn_idx[e];
    float a0 = pos[(size_t)ip*3+0], a1 = pos[(size_t)ip*3+1], a2 = pos[(size_t)ip*3+2];
    float c0 = pos[(size_t)jp*3+0], c1 = pos[(size_t)jp*3+1], c2 = pos[(size_t)jp*3+2];
    ef[t][0] = a0; ef[t][1] = a1; ef[t][2] = a2;
    ef[t][3] = c0 - a0; ef[t][4] = c1 - a1; ef[t][5] = c2 - a2;
    bl[t] = bias[t];
  }
  for (int idx = t; idx < 6*64; idx += 256) Wl[idx>>6][idx&63] = W[idx];
  __syncthreads();
  const int c = t & 63, rs = t >> 6;
  double s = 0.0, ss = 0.0;
  for (int r = rs; r < 64; r += 4) {
    float acc = bl[c];
    #pragma unroll
    for (int q = 0; q < 6; ++q) acc = fmaf(ef[r][q], Wl[q][c], acc);
    acc = fmaxf(acc, 0.0f);
    hout[(size_t)(ebase + r)*64 + c] = acc;
    s += acc; ss += (double)acc * (double)acc;
  }
  red[t] = s; __syncthreads();
  if (t < 64) psum[(size_t)blk*64 + t] = red[t] + red[t+64] + red[t+128] + red[t+192];
  __syncthreads();
  red[t] = ss; __syncthreads();
  if (t < 64) psq[(size_t)blk*64 + t] = red[t] + red[t+64] + red[t+128] + red[t+192];
}

// ------------------- BN stats -> per-channel affine (block per channel)
__global__ __launch_bounds__(256) void stats_reduce_kernel(const double* __restrict__ psum,
    const double* __restrict__ psq, int nblk, int C, double invN,
    const float* __restrict__ g, const float* __restrict__ be,
    float2* __restrict__ aff) {
  __shared__ double rs[256];
  __shared__ double rq[256];
  const int c = blockIdx.x;          // grid = C
  const int t = threadIdx.x;
  double s = 0.0, ss = 0.0;
  for (int i = t; i < nblk; i += 256) {
    s  += psum[(size_t)i*C + c];
    ss += psq [(size_t)i*C + c];
  }
  rs[t] = s; rq[t] = ss; __syncthreads();
  for (int off = 128; off > 0; off >>= 1) {
    if (t < off) { rs[t] += rs[t+off]; rq[t] += rq[t+off]; }
    __syncthreads();
  }
  if (t == 0) {
    double mean = rs[0] * invN;
    double var = rq[0] * invN - mean*mean;
    var = var < 0.0 ? 0.0 : var;
    double inv = 1.0 / sqrt(var + 1e-5);
    float a = (float)((double)g[c] * inv);
    float off2 = (float)((double)be[c] - (double)g[c] * mean * inv);
    aff[c] = make_float2(a, off2);
  }
}

// -------------------------------- EdgeConv1 layers 2/3 (64 -> 64) + stats
__global__ __launch_bounds__(256) void ec_l64_kernel(const float* __restrict__ hin,
    const float2* __restrict__ affprev, const float* __restrict__ W,
    const float* __restrict__ bias, float* __restrict__ hout,
    double* __restrict__ psum, double* __restrict__ psq) {
  __shared__ float ein[64][68];
  __shared__ float Wl[64][64];
  __shared__ float2 affl[64];
  __shared__ float bl[64];
  __shared__ double redS[16][64];
  __shared__ double redQ[16][64];
  const int blk = blockIdx.x, t = threadIdx.x;
  const size_t ebase = (size_t)blk * 64;
  if (t < 64) { affl[t] = affprev[t]; bl[t] = bias[t]; }
  __syncthreads();
  for (int idx = t; idx < 64*64; idx += 256) {
    int r = idx >> 6, c = idx & 63;
    float2 ac = affl[c];
    ein[r][c] = fmaf(hin[ebase*64 + idx], ac.x, ac.y);
    Wl[r][c] = W[idx];
  }
  __syncthreads();
  const int c4 = t & 15, rs = t >> 4;
  const int cbase = c4 * 4;
  const int rbase = rs * 4;
  float acc[4][4];
  #pragma unroll
  for (int ii = 0; ii < 4; ++ii) {
    #pragma unroll
    for (int jj = 0; jj < 4; ++jj) acc[ii][jj] = bl[cbase + jj];
  }
  for (int cin = 0; cin < 64; cin += 4) {
    float4 fi[4];
    #pragma unroll
    for (int ii = 0; ii < 4; ++ii) fi[ii] = *(const float4*)&ein[rbase+ii][cin];
    #pragma unroll
    for (int q = 0; q < 4; ++q) {
      float4 wv = *(const float4*)&Wl[cin+q][cbase];
      #pragma unroll
      for (int ii = 0; ii < 4; ++ii) {
        float f = f4c(fi[ii], q);
        acc[ii][0] = fmaf(f, wv.x, acc[ii][0]);
        acc[ii][1] = fmaf(f, wv.y, acc[ii][1]);
        acc[ii][2] = fmaf(f, wv.z, acc[ii][2]);
        acc[ii][3] = fmaf(f, wv.w, acc[ii][3]);
      }
    }
  }
  double s[4] = {0,0,0,0}, ss[4] = {0,0,0,0};
  #pragma unroll
  for (int ii = 0; ii < 4; ++ii) {
    float4 h;
    h.x = fmaxf(acc[ii][0], 0.f); h.y = fmaxf(acc[ii][1], 0.f);
    h.z = fmaxf(acc[ii][2], 0.f); h.w = fmaxf(acc[ii][3], 0.f);
    *(float4*)&hout[(ebase + rbase + ii)*64 + cbase] = h;
    s[0]+=h.x; s[1]+=h.y; s[2]+=h.z; s[3]+=h.w;
    ss[0]+=(double)h.x*h.x; ss[1]+=(double)h.y*h.y;
    ss[2]+=(double)h.z*h.z; ss[3]+=(double)h.w*h.w;
  }
  #pragma unroll
  for (int jj = 0; jj < 4; ++jj) { redS[rs][cbase+jj] = s[jj]; redQ[rs][cbase+jj] = ss[jj]; }
  __syncthreads();
  if (t < 64) {
    double a = 0, bq = 0;
    #pragma unroll
    for (int r = 0; r < 16; ++r) { a += redS[r][t]; bq += redQ[r][t]; }
    psum[(size_t)blk*64 + t] = a;
    psq[(size_t)blk*64 + t] = bq;
  }
}

// ------------------------------------ max over k with BN affine (monotone)
__global__ void ec1_reduce_kernel(const float* __restrict__ h3,
    const float2* __restrict__ aff, float* __restrict__ x1) {
  int idx = blockIdx.x * 256 + threadIdx.x;
  if (idx >= NPT * 64) return;
  int p = idx >> 6, c = idx & 63;
  float mx = -FINF, mn = FINF;
  #pragma unroll
  for (int kk = 0; kk < KNN; ++kk) {
    float v = h3[((size_t)p*KNN + kk)*64 + c];
    mx = fmaxf(mx, v); mn = fminf(mn, v);
  }
  float2 ac = aff[c];
  x1[idx] = (ac.x >= 0.f) ? fmaf(ac.x, mx, ac.y) : fmaf(ac.x, mn, ac.y);
}

// ----------------------------- |x1|^2 per point (same fmaf order as before)
__global__ void sq_kernel(const float* __restrict__ x1, float* __restrict__ sqg) {
  int p = blockIdx.x * 256 + threadIdx.x;
  if (p >= NPT) return;
  const float* row = &x1[(size_t)p * 64];
  float s = 0.f;
  #pragma unroll
  for (int c = 0; c < 64; ++c) s = fmaf(row[c], row[c], s);
  sqg[p] = s;
}

// ----------------------------- x1 -> hi/lo bf16 split (hoisted once)
__global__ void hl_kernel(const float* __restrict__ x1, ushort* __restrict__ x1hi,
                          ushort* __restrict__ x1lo) {
  int idx = blockIdx.x * 256 + threadIdx.x;
  int o = idx * 4;
  float4 v = *(const float4*)&x1[o];
  ushort4 h, lo;
  h.x = f2bf(v.x); lo.x = f2bf(v.x - bf2f(h.x));
  h.y = f2bf(v.y); lo.y = f2bf(v.y - bf2f(h.y));
  h.z = f2bf(v.z); lo.z = f2bf(v.z - bf2f(h.z));
  h.w = f2bf(v.w); lo.w = f2bf(v.w - bf2f(h.w));
  *(ushort4*)&x1hi[o] = h;
  *(ushort4*)&x1lo[o] = lo;
}

// ---------------------------------------------------------------- knn (64-d)
// R20: j-scan split into QUARTERS (grid = NB*16*4 = 2048 blocks, 4 j-tiles
// each); xi frags in registers (R19); LDS 18.4KB -> true 8 blocks/CU.
__global__ __launch_bounds__(256, 8) void knn2_kernel(const ushort* __restrict__ x1hi,
    const ushort* __restrict__ x1lo, const float* __restrict__ sqg,
    float* __restrict__ kpd, int* __restrict__ kpj) {
  __shared__ __align__(16) char smem[18432];
  ushort* xjhi = (ushort*)smem;                 // [64][72]
  ushort* xjlo = (ushort*)(smem + 9216);        // [64][72]
  float*  dist = (float*)smem;                  // [64][68] f32, aliases xj after MFMA
  const int b = blockIdx.x >> 6;
  const int it = (blockIdx.x >> 2) & 15;
  const int quarter = blockIdx.x & 3;
  const int t = threadIdx.x;
  const int ibase = it * 64;  // within batch

  // stage xi through the xj buffers ONCE, then hoist this wave's A-frags
  #pragma unroll
  for (int i = 0; i < 2; ++i) {
    int idx = i*256 + t;
    int r = idx >> 3, c8 = (idx & 7) * 8;
    *(bf16x8*)&xjhi[r*72 + c8] = *(const bf16x8*)&x1hi[((size_t)b*NP + ibase + r)*64 + c8];
    *(bf16x8*)&xjlo[r*72 + c8] = *(const bf16x8*)&x1lo[((size_t)b*NP + ibase + r)*64 + c8];
  }
  __syncthreads();

  const int w = t >> 6, l = t & 63;
  const int lr = l & 15, lg = l >> 4;
  const int row = t >> 2, ql = t & 3;
  const bf16x8 ah0 = *(const bf16x8*)&xjhi[(w*16 + lr)*72 +  0 + lg*8];
  const bf16x8 al0 = *(const bf16x8*)&xjlo[(w*16 + lr)*72 +  0 + lg*8];
  const bf16x8 ah1 = *(const bf16x8*)&xjhi[(w*16 + lr)*72 + 32 + lg*8];
  const bf16x8 al1 = *(const bf16x8*)&xjlo[(w*16 + lr)*72 + 32 + lg*8];
  float si2[4];
  #pragma unroll
  for (int ii = 0; ii < 4; ++ii)
    si2[ii] = sqg[(size_t)b*NP + ibase + w*16 + lg*4 + ii];

  float d0=FINF,d1=FINF,d2=FINF,d3=FINF,d4=FINF;
  int j0=0x7fffffff,j1=0x7fffffff,j2=0x7fffffff,j3=0x7fffffff,j4=0x7fffffff;

  for (int jt = 0; jt < 4; ++jt) {
    const int jtg = quarter * 4 + jt;
    __syncthreads();   // frag loads done (first iter) / prev selection done
    #pragma unroll
    for (int i = 0; i < 2; ++i) {
      int idx = i*256 + t;
      int r = idx >> 3, c8 = (idx & 7) * 8;
      *(bf16x8*)&xjhi[r*72 + c8] = *(const bf16x8*)&x1hi[((size_t)b*NP + jtg*64 + r)*64 + c8];
      *(bf16x8*)&xjlo[r*72 + c8] = *(const bf16x8*)&x1lo[((size_t)b*NP + jtg*64 + r)*64 + c8];
    }
    __syncthreads();
    f32x4 acc0 = (f32x4){0.f,0.f,0.f,0.f};
    f32x4 acc1 = (f32x4){0.f,0.f,0.f,0.f};
    f32x4 acc2 = (f32x4){0.f,0.f,0.f,0.f};
    f32x4 acc3 = (f32x4){0.f,0.f,0.f,0.f};
    #pragma unroll
    for (int ks = 0; ks < 2; ++ks) {
      const int k0 = ks * 32;
      const bf16x8 ah = ks ? ah1 : ah0;   // compile-time select (unrolled)
      const bf16x8 al = ks ? al1 : al0;
      {
        bf16x8 bh = *(const bf16x8*)&xjhi[(0*16 + lr)*72 + k0 + lg*8];
        bf16x8 bl = *(const bf16x8*)&xjlo[(0*16 + lr)*72 + k0 + lg*8];
        acc0 = __builtin_amdgcn_mfma_f32_16x16x32_bf16(ah, bh, acc0, 0, 0, 0);
        acc0 = __builtin_amdgcn_mfma_f32_16x16x32_bf16(ah, bl, acc0, 0, 0, 0);
        acc0 = __builtin_amdgcn_mfma_f32_16x16x32_bf16(al, bh, acc0, 0, 0, 0);
        acc0 = __builtin_amdgcn_mfma_f32_16x16x32_bf16(al, bl, acc0, 0, 0, 0);
      }
      {
        bf16x8 bh = *(const bf16x8*)&xjhi[(1*16 + lr)*72 + k0 + lg*8];
        bf16x8 bl = *(const bf16x8*)&xjlo[(1*16 + lr)*72 + k0 + lg*8];
        acc1 = __builtin_amdgcn_mfma_f32_16x16x32_bf16(ah, bh, acc1, 0, 0, 0);
        acc1 = __builtin_amdgcn_mfma_f32_16x16x32_bf16(ah, bl, acc1, 0, 0, 0);
        acc1 = __builtin_amdgcn_mfma_f32_16x16x32_bf16(al, bh, acc1, 0, 0, 0);
        acc1 = __builtin_amdgcn_mfma_f32_16x16x32_bf16(al, bl, acc1, 0, 0, 0);
      }
      {
        bf16x8 bh = *(const bf16x8*)&xjhi[(2*16 + lr)*72 + k0 + lg*8];
        bf16x8 bl = *(const bf16x8*)&xjlo[(2*16 + lr)*72 + k0 + lg*8];
        acc2 = __builtin_amdgcn_mfma_f32_16x16x32_bf16(ah, bh, acc2, 0, 0, 0);
        acc2 = __builtin_amdgcn_mfma_f32_16x16x32_bf16(ah, bl, acc2, 0, 0, 0);
        acc2 = __builtin_amdgcn_mfma_f32_16x16x32_bf16(al, bh, acc2, 0, 0, 0);
        acc2 = __builtin_amdgcn_mfma_f32_16x16x32_bf16(al, bl, acc2, 0, 0, 0);
      }
      {
        bf16x8 bh = *(const bf16x8*)&xjhi[(3*16 + lr)*72 + k0 + lg*8];
        bf16x8 bl = *(const bf16x8*)&xjlo[(3*16 + lr)*72 + k0 + lg*8];
        acc3 = __builtin_amdgcn_mfma_f32_16x16x32_bf16(ah, bh, acc3, 0, 0, 0);
        acc3 = __builtin_amdgcn_mfma_f32_16x16x32_bf16(ah, bl, acc3, 0, 0, 0);
        acc3 = __builtin_amdgcn_mfma_f32_16x16x32_bf16(al, bh, acc3, 0, 0, 0);
        acc3 = __builtin_amdgcn_mfma_f32_16x16x32_bf16(al, bl, acc3, 0, 0, 0);
      }
    }
    float sjv0 = sqg[(size_t)b*NP + jtg*64 + 0*16 + lr];
    float sjv1 = sqg[(size_t)b*NP + jtg*64 + 1*16 + lr];
    float sjv2 = sqg[(size_t)b*NP + jtg*64 + 2*16 + lr];
    float sjv3 = sqg[(size_t)b*NP + jtg*64 + 3*16 + lr];
    __syncthreads();   // all MFMA LDS reads done; dist aliases xj region
    #pragma unroll
    for (int ii = 0; ii < 4; ++ii) {
      const int irow = w*16 + lg*4 + ii;
      dist[irow*68 + 0*16 + lr] = fmaf(-2.f, acc0[ii], si2[ii] + sjv0);
      dist[irow*68 + 1*16 + lr] = fmaf(-2.f, acc1[ii], si2[ii] + sjv1);
      dist[irow*68 + 2*16 + lr] = fmaf(-2.f, acc2[ii], si2[ii] + sjv2);
      dist[irow*68 + 3*16 + lr] = fmaf(-2.f, acc3[ii], si2[ii] + sjv3);
    }
    __syncthreads();
    const int jgbase = jtg*64 + ql*16;   // ascending within lane -> insert5f
    #pragma unroll
    for (int kk = 0; kk < 4; ++kk) {
      float4 v = *(const float4*)&dist[row*68 + ql*16 + 4*kk];
      insert5f(d0,d1,d2,d3,d4, j0,j1,j2,j3,j4, v.x, jgbase + 4*kk + 0);
      insert5f(d0,d1,d2,d3,d4, j0,j1,j2,j3,j4, v.y, jgbase + 4*kk + 1);
      insert5f(d0,d1,d2,d3,d4, j0,j1,j2,j3,j4, v.z, jgbase + 4*kk + 2);
      insert5f(d0,d1,d2,d3,d4, j0,j1,j2,j3,j4, v.w, jgbase + 4*kk + 3);
    }
  }

  #pragma unroll
  for (int m = 1; m <= 2; m <<= 1) {
    float e0 = __shfl_xor(d0, m, 4), e1 = __shfl_xor(d1, m, 4),
          e2 = __shfl_xor(d2, m, 4), e3 = __shfl_xor(d3, m, 4),
          e4 = __shfl_xor(d4, m, 4);
    int   k0 = __shfl_xor(j0, m, 4), k1 = __shfl_xor(j1, m, 4),
          k2 = __shfl_xor(j2, m, 4), k3 = __shfl_xor(j3, m, 4),
          k4 = __shfl_xor(j4, m, 4);
    insert5(d0,d1,d2,d3,d4, j0,j1,j2,j3,j4, e0, k0);
    insert5(d0,d1,d2,d3,d4, j0,j1,j2,j3,j4, e1, k1);
    insert5(d0,d1,d2,d3,d4, j0,j1,j2,j3,j4, e2, k2);
    insert5(d0,d1,d2,d3,d4, j0,j1,j2,j3,j4, e3, k3);
    insert5(d0,d1,d2,d3,d4, j0,j1,j2,j3,j4, e4, k4);
  }
  if (ql == 0) {
    const size_t orow = ((size_t)quarter*NPT + (size_t)b*NP + ibase + row) * KNN;
    kpd[orow+0] = d0; kpd[orow+1] = d1; kpd[orow+2] = d2; kpd[orow+3] = d3; kpd[orow+4] = d4;
    kpj[orow+0] = j0; kpj[orow+1] = j1; kpj[orow+2] = j2; kpj[orow+3] = j3; kpj[orow+4] = j4;
  }
}

// merge the four sorted quarter top-5 lists (full lex == stable top-k)
__global__ void knn2_merge_kernel(const float* __restrict__ kpd,
    const int* __restrict__ kpj, int* __restrict__ knn_idx) {
  int r = blockIdx.x * 256 + threadIdx.x;
  if (r >= NPT) return;
  const int b = r >> 10;
  const size_t r0 = (size_t)r * KNN;
  float d0 = kpd[r0+0], d1 = kpd[r0+1], d2 = kpd[r0+2], d3 = kpd[r0+3], d4 = kpd[r0+4];
  int   j0 = kpj[r0+0], j1 = kpj[r0+1], j2 = kpj[r0+2], j3 = kpj[r0+3], j4 = kpj[r0+4];
  #pragma unroll
  for (int q = 1; q < 4; ++q) {
    const size_t rq = ((size_t)q*NPT + r) * KNN;
    #pragma unroll
    for (int s = 0; s < KNN; ++s) {
      insert5(d0,d1,d2,d3,d4, j0,j1,j2,j3,j4, kpd[rq+s], kpj[rq+s]);
    }
  }
  knn_idx[r0+0] = b*NP + j0;
  knn_idx[r0+1] = b*NP + j1;
  knn_idx[r0+2] = b*NP + j2;
  knn_idx[r0+3] = b*NP + j3;
  knn_idx[r0+4] = b*NP + j4;
}

// -------- W2[128][128] f32 -> split bf16 FRAGMENT-ORDER
__global__ __launch_bounds__(256) void wt2_kernel(const float* __restrict__ W,
    ushort* __restrict__ WthiF, ushort* __restrict__ WtloF) {
  __shared__ ushort lsh[64][128];
  __shared__ ushort lsl[64][128];
  const int cbase = blockIdx.x * 64;   // grid = 2
  const int t = threadIdx.x;
  for (int idx = t; idx < 128 * 64; idx += 256) {
    int cc = idx & 63, k = idx >> 6;
    float w = W[(size_t)k * 128 + cbase + cc];
    ushort hi = f2bf(w);
    ushort lo = f2bf(w - bf2f(hi));
    lsh[cc][k] = hi; lsl[cc][k] = lo;
  }
  __syncthreads();
  const int ctl = t >> 6, lane = t & 63;
  const int lr = lane & 15, lg = lane >> 4;
  const int ctg = (cbase >> 4) + ctl;
  #pragma unroll
  for (int ks = 0; ks < 4; ++ks) {
    size_t o = ((size_t)(ctg*4 + ks)*64 + lane) * 8;
    *(bf16x8*)&WthiF[o] = *(const bf16x8*)&lsh[ctl*16 + lr][ks*32 + lg*8];
    *(bf16x8*)&WtloF[o] = *(const bf16x8*)&lsl[ctl*16 + lr][ks*32 + lg*8];
  }
}

// ------------ EdgeConv2 (128 -> 128) SPLIT bf16 MFMA + k-max/min + stats
#define EC2S 136
__global__ __launch_bounds__(256) void ec2_kernel(const float* __restrict__ x1,
    const int* __restrict__ knn_idx, const ushort* __restrict__ WthiF,
    const ushort* __restrict__ WtloF, const float* __restrict__ bias,
    float* __restrict__ x2max, float* __restrict__ x2min,
    double* __restrict__ psum, double* __restrict__ psq) {
  __shared__ __align__(16) char smem[2 * 40 * EC2S * 2];  // 21.76 KB
  ushort* Ahi = (ushort*)smem;                       // 40*EC2S
  ushort* Alo = (ushort*)(smem + 40 * EC2S * 2);     // 40*EC2S
  float (*outs)[132] = (float (*)[132])smem;         // [40][132] aliases after GEMM
  double (*redS)[128] = (double (*)[128])smem;              // aliases after epilogue
  double (*redQ)[128] = (double (*)[128])(smem + 4*128*8);  // 8 KB total
  const int blk = blockIdx.x, t = threadIdx.x;       // grid = NPT/8
  const int pbase = blk * 8;
  // staging: 40 rows x 32 float4-groups
  for (int idx = t; idx < 40 * 32; idx += 256) {
    int r = idx >> 5, c4 = (idx & 31) * 4;
    int p = pbase + r / KNN;
    int kk = r % KNN;
    float4 v;
    if (c4 < 64) {
      v = *(const float4*)&x1[(size_t)p * 64 + c4];
    } else {
      int cc = c4 - 64;
      int j = knn_idx[(size_t)p * KNN + kk];
      float4 vj = *(const float4*)&x1[(size_t)j * 64 + cc];
      float4 vp = *(const float4*)&x1[(size_t)p * 64 + cc];
      v = make_float4(vj.x - vp.x, vj.y - vp.y, vj.z - vp.z, vj.w - vp.w);
    }
    ushort4 h, lo;
    h.x = f2bf(v.x); lo.x = f2bf(v.x - bf2f(h.x));
    h.y = f2bf(v.y); lo.y = f2bf(v.y - bf2f(h.y));
    h.z = f2bf(v.z); lo.z = f2bf(v.z - bf2f(h.z));
    h.w = f2bf(v.w); lo.w = f2bf(v.w - bf2f(h.w));
    *(ushort4*)&Ahi[r * EC2S + c4] = h;
    *(ushort4*)&Alo[r * EC2S + c4] = lo;
  }
  __syncthreads();
  const int l = t & 63, w = t >> 6;
  const int lr = l & 15, lg = l >> 4;
  f32x4 acc[3][2];
  #pragma unroll
  for (int rt = 0; rt < 3; ++rt) {
    acc[rt][0] = (f32x4){0.f,0.f,0.f,0.f};
    acc[rt][1] = (f32x4){0.f,0.f,0.f,0.f};
  }
  #pragma unroll
  for (int ks = 0; ks < 4; ++ks) {
    const int k0 = ks * 32;
    bf16x8 bh0 = *(const bf16x8*)&WthiF[((size_t)((2*w  )*4 + ks)*64 + l)*8];
    bf16x8 bh1 = *(const bf16x8*)&WthiF[((size_t)((2*w+1)*4 + ks)*64 + l)*8];
    bf16x8 bl0 = *(const bf16x8*)&WtloF[((size_t)((2*w  )*4 + ks)*64 + l)*8];
    bf16x8 bl1 = *(const bf16x8*)&WtloF[((size_t)((2*w+1)*4 + ks)*64 + l)*8];
    #pragma unroll
    for (int rt = 0; rt < 3; ++rt) {
      int ar = rt*16 + lr;
      int arc = ar < 40 ? ar : 39;   // clamp pad reads in-bounds (values unused)
      bf16x8 ah = *(const bf16x8*)&Ahi[arc * EC2S + k0 + lg*8];
      bf16x8 al = *(const bf16x8*)&Alo[arc * EC2S + k0 + lg*8];
      acc[rt][0] = __builtin_amdgcn_mfma_f32_16x16x32_bf16(ah, bh0, acc[rt][0], 0, 0, 0);
      acc[rt][0] = __builtin_amdgcn_mfma_f32_16x16x32_bf16(ah, bl0, acc[rt][0], 0, 0, 0);
      acc[rt][0] = __builtin_amdgcn_mfma_f32_16x16x32_bf16(al, bh0, acc[rt][0], 0, 0, 0);
      acc[rt][1] = __builtin_amdgcn_mfma_f32_16x16x32_bf16(ah, bh1, acc[rt][1], 0, 0, 0);
      acc[rt][1] = __builtin_amdgcn_mfma_f32_16x16x32_bf16(ah, bl1, acc[rt][1], 0, 0, 0);
      acc[rt][1] = __builtin_amdgcn_mfma_f32_16x16x32_bf16(al, bh1, acc[rt][1], 0, 0, 0);
    }
  }
  __syncthreads();   // all Ahi/Alo reads done before outs aliases them
  {
    const float bv0 = bias[w*32 + lr];
    const float bv1 = bias[w*32 + 16 + lr];
    #pragma unroll
    for (int rt = 0; rt < 3; ++rt) {
      #pragma unroll
      for (int i = 0; i < 4; ++i) {
        int e = rt*16 + lg*4 + i;
        if (e < 40) {
          outs[e][w*32 + lr]      = fmaxf(acc[rt][0][i] + bv0, 0.f);
          outs[e][w*32 + 16 + lr] = fmaxf(acc[rt][1][i] + bv1, 0.f);
        }
      }
    }
  }
  __syncthreads();
  // per-point k-max/min; per-thread stats held in regs
  double s4[4] = {0,0,0,0}, q4[4] = {0,0,0,0};
  {
    const int p = t >> 5;             // 8 points, 32 threads each
    const int cs = (t & 31) * 4;      // 4 cols per thread
    float4 mx = make_float4(-FINF,-FINF,-FINF,-FINF);
    float4 mn = make_float4(FINF,FINF,FINF,FINF);
    #pragma unroll
    for (int kk = 0; kk < KNN; ++kk) {
      float4 va = *(const float4*)&outs[p*KNN + kk][cs];
      mx.x = fmaxf(mx.x, va.x); mn.x = fminf(mn.x, va.x); s4[0] += va.x; q4[0] += (double)va.x*va.x;
      mx.y = fmaxf(mx.y, va.y); mn.y = fminf(mn.y, va.y); s4[1] += va.y; q4[1] += (double)va.y*va.y;
      mx.z = fmaxf(mx.z, va.z); mn.z = fminf(mn.z, va.z); s4[2] += va.z; q4[2] += (double)va.z*va.z;
      mx.w = fmaxf(mx.w, va.w); mn.w = fminf(mn.w, va.w); s4[3] += va.w; q4[3] += (double)va.w*va.w;
    }
    *(float4*)&x2max[((size_t)pbase + p)*128 + cs] = mx;
    *(float4*)&x2min[((size_t)pbase + p)*128 + cs] = mn;
    // reduce across the 2 points of this wave (lanes l and l^32)
    #pragma unroll
    for (int cc = 0; cc < 4; ++cc) {
      s4[cc] += __shfl_xor(s4[cc], 32);
      q4[cc] += __shfl_xor(q4[cc], 32);
    }
  }
  __syncthreads();   // all outs reads done; redS/redQ alias smem
  {
    const int cs = (t & 31) * 4;
    if ((t & 63) < 32) {
      #pragma unroll
      for (int cc = 0; cc < 4; ++cc) {
        redS[t >> 6][cs + cc] = s4[cc];
        redQ[t >> 6][cs + cc] = q4[cc];
      }
    }
  }
  __syncthreads();
  if (t < 128) {
    double a = redS[0][t] + redS[1][t] + redS[2][t] + redS[3][t];
    double q = redQ[0][t] + redQ[1][t] + redQ[2][t] + redQ[3][t];
    psum[(size_t)blk*128 + t] = a;
    psq [(size_t)blk*128 + t] = q;
  }
}

// ------- x2 = BN-affine(x2max/x2min) -> bf16, ONCE
__global__ void x2c_kernel(const float* __restrict__ x2max,
    const float* __restrict__ x2min, const float2* __restrict__ aff2,
    ushort* __restrict__ x2bf) {
  int idx = blockIdx.x * 256 + threadIdx.x;   // grid = NPT*128/1024
  int o = idx * 4;
  int c4 = o & 127;
  float4 vmx = *(const float4*)&x2max[o];
  float4 vmn = *(const float4*)&x2min[o];
  float2 a0 = aff2[c4+0], a1 = aff2[c4+1], a2 = aff2[c4+2], a3 = aff2[c4+3];
  ushort4 hv;
  hv.x = f2bf((a0.x >= 0.f) ? fmaf(a0.x, vmx.x, a0.y) : fmaf(a0.x, vmn.x, a0.y));
  hv.y = f2bf((a1.x >= 0.f) ? fmaf(a1.x, vmx.y, a1.y) : fmaf(a1.x, vmn.y, a1.y));
  hv.z = f2bf((a2.x >= 0.f) ? fmaf(a2.x, vmx.z, a2.y) : fmaf(a2.x, vmn.z, a2.y));
  hv.w = f2bf((a3.x >= 0.f) ? fmaf(a3.x, vmx.w, a3.y) : fmaf(a3.x, vmn.w, a3.y));
  *(ushort4*)&x2bf[o] = hv;
}

// ---- W[192][1024] f32 -> bf16 FRAGMENT-ORDER
__global__ __launch_bounds__(256) void wt_kernel(const float* __restrict__ W,
                                                 ushort* __restrict__ WtF) {
  __shared__ ushort ls[64][192];
  const int cbase = blockIdx.x * 64;   // grid = 16
  const int t = threadIdx.x;
  for (int idx = t; idx < 192 * 64; idx += 256) {
    int cc = idx & 63, k = idx >> 6;
    ls[cc][k] = f2bf(W[(size_t)k * 1024 + cbase + cc]);
  }
  __syncthreads();
  const int ctl = t >> 6, lane = t & 63;
  const int lr = lane & 15, lg = lane >> 4;
  const int ctg = (cbase >> 4) + ctl;
  #pragma unroll
  for (int ks = 0; ks < 6; ++ks) {
    size_t o = ((size_t)(ctg*6 + ks)*64 + lane) * 8;
    *(bf16x8*)&WtF[o] = *(const bf16x8*)&ls[ctl*16 + lr][ks*32 + lg*8];
  }
}

// ------------- Lin1 (192 -> 1024) bf16 MFMA, fused ReLU + stats + max/min
__global__ __launch_bounds__(256) void lin1_kernel(const ushort* __restrict__ x1hi,
    const ushort* __restrict__ x2bf, const ushort* __restrict__ WtF,
    const float* __restrict__ bias, double* __restrict__ psum,
    double* __restrict__ psq, float* __restrict__ pmax, float* __restrict__ pmin) {
  __shared__ ushort As[64 * 208];   // 64 rows x 192 bf16, stride 208
  const int blk = blockIdx.x, t = threadIdx.x;
  const int brow = blk >> 1;          // 512 row tiles
  const int ch = blk & 1;             // col half (512 cols)
  const int pbase = brow * 64;
  #pragma unroll
  for (int i = 0; i < 2; ++i) {
    int idx = i*256 + t;
    int r = idx >> 3, c8 = (idx & 7) * 8;
    *(bf16x8*)&As[r*208 + c8] = *(const bf16x8*)&x1hi[((size_t)pbase + r)*64 + c8];
  }
  #pragma unroll
  for (int i = 0; i < 4; ++i) {
    int idx = i*256 + t;
    int r = idx >> 4, c8 = (idx & 15) * 8;
    *(bf16x8*)&As[r*208 + 64 + c8] = *(const bf16x8*)&x2bf[((size_t)pbase + r)*128 + c8];
  }
  __syncthreads();
  const int l = t & 63, w = t >> 6;
  const int lr = l & 15, lg = l >> 4;
  f32x4 acc[8][4];
  #pragma unroll
  for (int ct = 0; ct < 8; ++ct) {
    #pragma unroll
    for (int rf = 0; rf < 4; ++rf) acc[ct][rf] = (f32x4){0.f, 0.f, 0.f, 0.f};
  }
  #pragma unroll
  for (int ks = 0; ks < 6; ++ks) {
    const int k0 = ks * 32;
    bf16x8 a0 = *(const bf16x8*)&As[( 0 + lr) * 208 + k0 + lg * 8];
    bf16x8 a1 = *(const bf16x8*)&As[(16 + lr) * 208 + k0 + lg * 8];
    bf16x8 a2 = *(const bf16x8*)&As[(32 + lr) * 208 + k0 + lg * 8];
    bf16x8 a3 = *(const bf16x8*)&As[(48 + lr) * 208 + k0 + lg * 8];
    #pragma unroll
    for (int ct = 0; ct < 8; ++ct) {
      bf16x8 bv = *(const bf16x8*)&WtF[((size_t)((ch*32 + w*8 + ct)*6 + ks)*64 + l)*8];
      acc[ct][0] = __builtin_amdgcn_mfma_f32_16x16x32_bf16(a0, bv, acc[ct][0], 0, 0, 0);
      acc[ct][1] = __builtin_amdgcn_mfma_f32_16x16x32_bf16(a1, bv, acc[ct][1], 0, 0, 0);
      acc[ct][2] = __builtin_amdgcn_mfma_f32_16x16x32_bf16(a2, bv, acc[ct][2], 0, 0, 0);
      acc[ct][3] = __builtin_amdgcn_mfma_f32_16x16x32_bf16(a3, bv, acc[ct][3], 0, 0, 0);
    }
  }
  #pragma unroll
  for (int ct = 0; ct < 8; ++ct) {
    const int c = ch*512 + w*128 + ct * 16 + lr;
    const float bv = bias[c];
    double s = 0.0, ss = 0.0;
    float mx = -FINF, mn = FINF;
    #pragma unroll
    for (int rf = 0; rf < 4; ++rf) {
      #pragma unroll
      for (int i = 0; i < 4; ++i) {
        float h = fmaxf(acc[ct][rf][i] + bv, 0.f);
        s += (double)h;
        ss += (double)h * h;
        mx = fmaxf(mx, h);
        mn = fminf(mn, h);
      }
    }
    s  += __shfl_xor(s, 16);  ss += __shfl_xor(ss, 16);
    mx = fmaxf(mx, __shfl_xor(mx, 16)); mn = fminf(mn, __shfl_xor(mn, 16));
    s  += __shfl_xor(s, 32);  ss += __shfl_xor(ss, 32);
    mx = fmaxf(mx, __shfl_xor(mx, 32)); mn = fminf(mn, __shfl_xor(mn, 32));
    if (lg == 0) {
      psum[(size_t)brow * 1024 + c] = s;
      psq [(size_t)brow * 1024 + c] = ss;
      pmax[(size_t)brow * 1024 + c] = mx;
      pmin[(size_t)brow * 1024 + c] = mn;
    }
  }
}

// ----------------- lin1 BN+maxpool finalize (block per channel; 512 partials)
__global__ __launch_bounds__(256) void lin1_fin_kernel(const double* __restrict__ psum,
    const double* __restrict__ psq, const float* __restrict__ pmax,
    const float* __restrict__ pmin, const float* __restrict__ g,
    const float* __restrict__ be, float* __restrict__ y) {
  __shared__ double rs[256];
  __shared__ double rq[256];
  __shared__ float smx[32][8];
  __shared__ float smn[32][8];
  __shared__ float sa[2];
  const int c = blockIdx.x;          // grid = 1024
  const int t = threadIdx.x;
  double s = 0.0, ss = 0.0;
  for (int i = t; i < 512; i += 256) {
    s  += psum[(size_t)i*1024 + c];
    ss += psq [(size_t)i*1024 + c];
  }
  rs[t] = s; rq[t] = ss; __syncthreads();
  for (int off = 128; off > 0; off >>= 1) {
    if (t < off) { rs[t] += rs[t+off]; rq[t] += rq[t+off]; }
    __syncthreads();
  }
  if (t == 0) {
    double mean = rs[0] / 32768.0;
    double var = rq[0] / 32768.0 - mean*mean;
    var = var < 0.0 ? 0.0 : var;
    double inv = 1.0 / sqrt(var + 1e-5);
    sa[0] = (float)((double)g[c] * inv);
    sa[1] = (float)((double)be[c] - (double)g[c]*mean*inv);
  }
  {
    int b = t >> 3, q = t & 7;
    float mxv = -FINF, mnv = FINF;
    #pragma unroll
    for (int k = 0; k < 2; ++k) {
      int i = b*16 + q*2 + k;
      mxv = fmaxf(mxv, pmax[(size_t)i*1024 + c]);
      mnv = fminf(mnv, pmin[(size_t)i*1024 + c]);
    }
    smx[b][q] = mxv;
    smn[b][q] = mnv;
  }
  __syncthreads();
  if (t < 32) {
    float mxv = -FINF, mnv = FINF;
    #pragma unroll
    for (int q = 0; q < 8; ++q) { mxv = fmaxf(mxv, smx[t][q]); mnv = fminf(mnv, smn[t][q]); }
    float a = sa[0], off2 = sa[1];
    y[(size_t)t*1024 + c] = (a >= 0.f) ? fmaf(a, mxv, off2) : fmaf(a, mnv, off2);
  }
}

// ---------------------------------------------------------------- head MLP
__global__ __launch_bounds__(256) void head1_kernel(const float* __restrict__ y,
    const float* __restrict__ W, const float* __restrict__ bias, float* __restrict__ h5) {
  __shared__ float yr[1024];
  __shared__ float part[256];
  const int r = blockIdx.x >> 2;
  const int cseg = (blockIdx.x & 3) * 128;
  const int t = threadIdx.x;
  for (int i = t; i < 1024; i += 256) yr[i] = y[(size_t)r*1024 + i];
  __syncthreads();
  const int c = cseg + (t & 127);
  const int kh = t >> 7;
  const int kbase = kh * 512;
  float a0 = 0.f, a1 = 0.f, a2 = 0.f, a3 = 0.f;
  for (int cin = 0; cin < 512; cin += 4) {
    a0 = fmaf(yr[kbase+cin+0], W[(size_t)(kbase+cin+0)*512 + c], a0);
    a1 = fmaf(yr[kbase+cin+1], W[(size_t)(kbase+cin+1)*512 + c], a1);
    a2 = fmaf(yr[kbase+cin+2], W[(size_t)(kbase+cin+2)*512 + c], a2);
    a3 = fmaf(yr[kbase+cin+3], W[(size_t)(kbase+cin+3)*512 + c], a3);
  }
  part[t] = ((a0 + a1) + (a2 + a3));
  __syncthreads();
  if (t < 128) {
    float acc = bias[c] + part[t] + part[t + 128];
    h5[(size_t)r*512 + c] = fmaxf(acc, 0.f);
  }
}

__global__ void bn_rows_kernel(const float* __restrict__ h, int C, int R,
    const float* __restrict__ g, const float* __restrict__ be, float2* __restrict__ aff) {
  int c = blockIdx.x*256 + threadIdx.x;
  if (c >= C) return;
  double s = 0, ss = 0;
  for (int r = 0; r < R; ++r) {
    double v = (double)h[(size_t)r*C + c];
    s += v; ss += v*v;
  }
  double mean = s / (double)R;
  double var = ss / (double)R - mean*mean;
  var = var < 0.0 ? 0.0 : var;
  double inv = 1.0 / sqrt(var + 1e-5);
  float a = (float)((double)g[c] * inv);
  float off = (float)((double)be[c] - (double)g[c]*mean*inv);
  aff[c] = make_float2(a, off);
}

__global__ __launch_bounds__(256) void head2_kernel(const float* __restrict__ h5,
    const float2* __restrict__ aff, const float* __restrict__ W,
    const float* __restrict__ bias, float* __restrict__ h6) {
  __shared__ float hr[512];
  const int r = blockIdx.x;            // grid = 32
  const int t = threadIdx.x;
  for (int i = t; i < 512; i += 256) {
    float2 a = aff[i];
    hr[i] = fmaf(a.x, h5[(size_t)r*512 + i], a.y);
  }
  __syncthreads();
  const int c = t;
  float a0 = 0.f, a1 = 0.f, a2 = 0.f, a3 = 0.f;
  for (int cin = 0; cin < 512; cin += 4) {
    a0 = fmaf(hr[cin+0], W[(size_t)(cin+0)*256 + c], a0);
    a1 = fmaf(hr[cin+1], W[(size_t)(cin+1)*256 + c], a1);
    a2 = fmaf(hr[cin+2], W[(size_t)(cin+2)*256 + c], a2);
    a3 = fmaf(hr[cin+3], W[(size_t)(cin+3)*256 + c], a3);
  }
  float acc = bias[c] + ((a0 + a1) + (a2 + a3));
  h6[(size_t)r*256 + c] = fmaxf(acc, 0.f);
}

__global__ void head3_kernel(const float* __restrict__ h6, const float2* __restrict__ aff,
    const float* __restrict__ W, const float* __restrict__ bias, float* __restrict__ out) {
  int t = threadIdx.x;
  if (t >= 64) return;
  int r = t >> 1, c = t & 1;
  float acc = bias[c];
  for (int cin = 0; cin < 256; ++cin) {
    float2 a = aff[cin];
    acc = fmaf(fmaf(a.x, h6[(size_t)r*256 + cin], a.y), W[(size_t)cin*2 + c], acc);
  }
  out[(size_t)r*2 + c] = acc;
}

// ------------------------------------------------------------------ launcher
extern "C" void kernel_launch(void* const* d_in, const int* in_sizes, int n_in,
                              void* d_out, int out_size, void* d_ws, size_t ws_size,
                              hipStream_t stream) {
  (void)in_sizes; (void)n_in; (void)out_size; (void)ws_size;
  const float* pos    = (const float*)d_in[0];
  const float* c1_w1  = (const float*)d_in[2];
  const float* c1_b1  = (const float*)d_in[3];
  const float* c1_g1  = (const float*)d_in[4];
  const float* c1_be1 = (const float*)d_in[5];
  const float* c1_w2  = (const float*)d_in[6];
  const float* c1_b2  = (const float*)d_in[7];
  const float* c1_g2  = (const float*)d_in[8];
  const float* c1_be2 = (const float*)d_in[9];
  const float* c1_w3  = (const float*)d_in[10];
  const float* c1_b3  = (const float*)d_in[11];
  const float* c1_g3  = (const float*)d_in[12];
  const float* c1_be3 = (const float*)d_in[13];
  const float* c2_w1  = (const float*)d_in[14];
  const float* c2_b1  = (const float*)d_in[15];
  const float* c2_g1  = (const float*)d_in[16];
  const float* c2_be1 = (const float*)d_in[17];
  const float* l1_w   = (const float*)d_in[18];
  const float* l1_b   = (const float*)d_in[19];
  const float* l1_g   = (const float*)d_in[20];
  const float* l1_be  = (const float*)d_in[21];
  const float* m1_w   = (const float*)d_in[22];
  const float* m1_b   = (const float*)d_in[23];
  const float* m1_g   = (const float*)d_in[24];
  const float* m1_be  = (const float*)d_in[25];
  const float* m2_w   = (const float*)d_in[26];
  const float* m2_b   = (const float*)d_in[27];
  const float* m2_g   = (const float*)d_in[28];
  const float* m2_be  = (const float*)d_in[29];
  const float* m3_w   = (const float*)d_in[30];
  const float* m3_b   = (const float*)d_in[31];

  char* ws = (char*)d_ws;
  size_t off = 0;
  auto alloc = [&](size_t bytes) -> void* {
    void* p = ws + off;
    off += (bytes + 255) & ~(size_t)255;
    return p;
  };
  int*    idx1 = (int*)alloc((size_t)NE * 4);
  int*    idx2 = (int*)alloc((size_t)NE * 4);
  float*  x1   = (float*)alloc((size_t)NPT * 64 * 4);
  float*  hA   = (float*)alloc((size_t)NE * 64 * 4);
  float*  hB   = (float*)alloc((size_t)NE * 64 * 4);
  double* psum = (double*)alloc((size_t)1048576 * 8);
  double* psq  = (double*)alloc((size_t)1048576 * 8);
  float*  pmax = (float*)alloc((size_t)1048576 * 4);
  float*  pmin = (float*)alloc((size_t)1048576 * 4);
  float2* affA = (float2*)alloc(64 * 8);
  float2* affB = (float2*)alloc(64 * 8);
  float2* affC = (float2*)alloc(64 * 8);
  float2* aff2 = (float2*)alloc(128 * 8);
  float2* affM1 = (float2*)alloc(512 * 8);
  float2* affM2 = (float2*)alloc(256 * 8);
  float*  y    = (float*)alloc((size_t)NB * 1024 * 4);
  float*  h5   = (float*)alloc((size_t)NB * 512 * 4);
  float*  h6   = (float*)alloc((size_t)NB * 256 * 4);
  ushort* WtF  = (ushort*)alloc((size_t)1024 * 192 * 2);
  ushort* Wt2hiF = (ushort*)alloc((size_t)128 * 128 * 2);
  ushort* Wt2loF = (ushort*)alloc((size_t)128 * 128 * 2);
  float*  sqg  = (float*)alloc((size_t)NPT * 4);
  ushort* x1hi = (ushort*)alloc((size_t)NPT * 64 * 2);
  ushort* x1lo = (ushort*)alloc((size_t)NPT * 64 * 2);
  ushort* x2bf = (ushort*)alloc((size_t)NPT * 128 * 2);
  float*  kpd  = (float*)alloc((size_t)4 * NPT * KNN * 4);
  int*    kpj  = (int*)alloc((size_t)4 * NPT * KNN * 4);
  float* x2max = hA;
  float* x2min = hA + (size_t)NPT * 128;

  // 0. weight conversions (fragment-order)
  wt_kernel<<<dim3(16), dim3(256), 0, stream>>>(l1_w, WtF);
  wt2_kernel<<<dim3(2), dim3(256), 0, stream>>>(c2_w1, Wt2hiF, Wt2loF);
  // 1. knn on positions
  knn1_kernel<<<dim3(NB*32), dim3(256), 0, stream>>>(pos, idx1);
  // 2. EdgeConv1 layer1
  ec1_l1_kernel<<<dim3(NE/64), dim3(256), 0, stream>>>(pos, idx1, c1_w1, c1_b1, hA, psum, psq);
  stats_reduce_kernel<<<dim3(64), dim3(256), 0, stream>>>(psum, psq, NE/64, 64, 1.0/NE, c1_g1, c1_be1, affA);
  // 3. layer2
  ec_l64_kernel<<<dim3(NE/64), dim3(256), 0, stream>>>(hA, affA, c1_w2, c1_b2, hB, psum, psq);
  stats_reduce_kernel<<<dim3(64), dim3(256), 0, stream>>>(psum, psq, NE/64, 64, 1.0/NE, c1_g2, c1_be2, affB);
  // 4. layer3
  ec_l64_kernel<<<dim3(NE/64), dim3(256), 0, stream>>>(hB, affB, c1_w3, c1_b3, hA, psum, psq);
  stats_reduce_kernel<<<dim3(64), dim3(256), 0, stream>>>(psum, psq, NE/64, 64, 1.0/NE, c1_g3, c1_be3, affC);
  // 5. max over k -> x1
  ec1_reduce_kernel<<<dim3(NPT*64/256), dim3(256), 0, stream>>>(hA, affC, x1);
  // 6. knn on features (quarter-split scan, R20)
  sq_kernel<<<dim3(NPT/256), dim3(256), 0, stream>>>(x1, sqg);
  hl_kernel<<<dim3(NPT*64/1024), dim3(256), 0, stream>>>(x1, x1hi, x1lo);
  knn2_kernel<<<dim3(NB*16*4), dim3(256), 0, stream>>>(x1hi, x1lo, sqg, kpd, kpj);
  knn2_merge_kernel<<<dim3(NPT/256), dim3(256), 0, stream>>>(kpd, kpj, idx2);
  // 7. EdgeConv2 split-bf16 MFMA (8 pts/block, block-level stats)
  ec2_kernel<<<dim3(NPT/8), dim3(256), 0, stream>>>(x1, idx2, Wt2hiF, Wt2loF, c2_b1, x2max, x2min, psum, psq);
  stats_reduce_kernel<<<dim3(128), dim3(256), 0, stream>>>(psum, psq, NPT/8, 128, 1.0/NE, c2_g1, c2_be1, aff2);
  // 7b. x2 BN+bf16 conversion
  x2c_kernel<<<dim3(NPT*128/1024), dim3(256), 0, stream>>>(x2max, x2min, aff2, x2bf);
  // 8. Lin1 bf16-MFMA fused (pure-copy staging)
  lin1_kernel<<<dim3(1024), dim3(256), 0, stream>>>(x1hi, x2bf, WtF, l1_b, psum, psq, pmax, pmin);
  lin1_fin_kernel<<<dim3(1024), dim3(256), 0, stream>>>(psum, psq, pmax, pmin, l1_g, l1_be, y);
  // 9. head
  head1_kernel<<<dim3(128), dim3(256), 0, stream>>>(y, m1_w, m1_b, h5);
  bn_rows_kernel<<<dim3(2), dim3(256), 0, stream>>>(h5, 512, NB, m1_g, m1_be, affM1);
  head2_kernel<<<dim3(32), dim3(256), 0, stream>>>(h5, affM1, m2_w, m2_b, h6);
  bn_rows_kernel<<<dim3(1), dim3(256), 0, stream>>>(h6, 256, NB, m2_g, m2_be, affM2);
  head3_kernel<<<dim3(1), dim3(64), 0, stream>>>(h6, affM2, m3_w, m3_b, (float*)d_out);
}

// Round 21
// 370.696 us; speedup vs baseline: 1.0468x; 1.0468x over previous
//
#include <hip/hip_runtime.h>

// DGCNN forward. R2: parallel stats. R3: spill-free knn2 selection.
// R4: knn1 8 lanes/query. R5: heads re-parallelized. R6: lin1 bf16 MFMA.
// R7: ec2 PLAIN bf16 FAILED. R8: revert+j-split. R9: ec2 2pts/thread.
// R10: ec2 split-bf16 MFMA. R11: knn2 split-MFMA. R12: fragment-order W.
// R13: ec2 staging vectorized. R14: knn2 hi/lo hoist + scan-order insert.
// R15: lin1 8ct x 4 row-frags. R16: x2 BN'd once. R17: ec2 8pts/block.
// R18: ec2 block-level stats on aliased LDS. R19/R20: knn2 occupancy
// attempts NEUTRAL (VALU-floor) -> knn2 reverted to R18 form. R21:
// EdgeConv1 tail fusion -- layer3 ec_l64_last (80 edges = 16 points per
// block; 5-row thread tile == one point's k-hood; per-point max/min in
// REGISTERS; hmax/hmin 16.8MB instead of per-edge hout 41.9MB) and
// x1c_kernel fusing ec1_reduce+sq+hl (one 16.8MB read). ~67MB HBM cut.

#define NB 32
#define NP 1024
#define NPT 32768       // NB*NP
#define KNN 5
#define NE 163840       // NPT*KNN

#define FINF 3.402823466e+38f

typedef __attribute__((ext_vector_type(8))) short bf16x8;
typedef __attribute__((ext_vector_type(4))) float f32x4;

__device__ __forceinline__ bool lex_less(float da, int ja, float db, int jb) {
  return (da < db) || (da == db && ja < jb);
}

__device__ __forceinline__ float f4c(const float4& v, int q) {
  return q == 0 ? v.x : (q == 1 ? v.y : (q == 2 ? v.z : v.w));
}

// f32 -> bf16 (round-to-nearest-even)
__device__ __forceinline__ ushort f2bf(float f) {
  union { float f; unsigned u; } v; v.f = f;
  unsigned r = (v.u + 0x7FFFu + ((v.u >> 16) & 1u)) >> 16;
  return (ushort)r;
}
__device__ __forceinline__ float bf2f(ushort h) {
  union { unsigned u; float f; } v; v.u = ((unsigned)h) << 16;
  return v.f;
}

// insert (dd,jj) into sorted-ascending 5-list, FULL lex (for merges)
__device__ __forceinline__ void insert5(float& d0, float& d1, float& d2, float& d3, float& d4,
                                        int& j0, int& j1, int& j2, int& j3, int& j4,
                                        float dd, int jj) {
  if (lex_less(dd, jj, d4, j4)) {
    bool L0 = lex_less(dd,jj,d0,j0), L1 = lex_less(dd,jj,d1,j1),
         L2 = lex_less(dd,jj,d2,j2), L3 = lex_less(dd,jj,d3,j3);
    d4 = L3 ? d3 : dd;              j4 = L3 ? j3 : jj;
    d3 = L3 ? (L2 ? d2 : dd) : d3;  j3 = L3 ? (L2 ? j2 : jj) : j3;
    d2 = L2 ? (L1 ? d1 : dd) : d2;  j2 = L2 ? (L1 ? j1 : jj) : j2;
    d1 = L1 ? (L0 ? d0 : dd) : d1;  j1 = L1 ? (L0 ? j0 : jj) : j1;
    d0 = L0 ? dd : d0;              j0 = L0 ? jj : j0;
  }
}

// scan-order insert: jj strictly greater than all listed ji -> plain <
__device__ __forceinline__ void insert5f(float& d0, float& d1, float& d2, float& d3, float& d4,
                                         int& j0, int& j1, int& j2, int& j3, int& j4,
                                         float dd, int jj) {
  if (dd < d4) {
    bool L0 = dd < d0, L1 = dd < d1, L2 = dd < d2, L3 = dd < d3;
    d4 = L3 ? d3 : dd;              j4 = L3 ? j3 : jj;
    d3 = L3 ? (L2 ? d2 : dd) : d3;  j3 = L3 ? (L2 ? j2 : jj) : j3;
    d2 = L2 ? (L1 ? d1 : dd) : d2;  j2 = L2 ? (L1 ? j1 : jj) : j2;
    d1 = L1 ? (L0 ? d0 : dd) : d1;  j1 = L1 ? (L0 ? j0 : jj) : j1;
    d0 = L0 ? dd : d0;              j0 = L0 ? jj : j0;
  }
}

// ---------------------------------------------------------------- knn (3-d)
__global__ __launch_bounds__(256) void knn1_kernel(const float* __restrict__ pos,
                                                   int* __restrict__ knn_idx) {
  __shared__ float4 xs4[NP];    // (x, y, z, |x|^2)
  const int b = blockIdx.x >> 5;
  const int seg = blockIdx.x & 31;
  const int t = threadIdx.x;
  for (int i = t; i < NP; i += 256) {
    float x0 = pos[(size_t)b*NP*3 + i*3 + 0];
    float x1 = pos[(size_t)b*NP*3 + i*3 + 1];
    float x2 = pos[(size_t)b*NP*3 + i*3 + 2];
    float sq = __fadd_rn(__fadd_rn(__fmul_rn(x0,x0), __fmul_rn(x1,x1)), __fmul_rn(x2,x2));
    xs4[i] = make_float4(x0, x1, x2, sq);
  }
  __syncthreads();
  const int q = t >> 3;
  const int ql = t & 7;
  const int i = seg * 32 + q;
  const float4 xi = xs4[i];
  const float sqi = xi.w;
  float d0=FINF,d1=FINF,d2=FINF,d3=FINF,d4=FINF;
  int j0=0x7fffffff,j1=0x7fffffff,j2=0x7fffffff,j3=0x7fffffff,j4=0x7fffffff;
  for (int jj = 0; jj < NP/8; ++jj) {
    const int j = jj*8 + ql;    // ascending within lane -> insert5f exact
    float4 v = xs4[j];
    float dot = __fadd_rn(__fadd_rn(__fmul_rn(xi.x,v.x), __fmul_rn(xi.y,v.y)), __fmul_rn(xi.z,v.z));
    float dd = __fsub_rn(__fadd_rn(sqi, v.w), __fmul_rn(2.0f, dot));
    insert5f(d0,d1,d2,d3,d4, j0,j1,j2,j3,j4, dd, j);
  }
  #pragma unroll
  for (int m = 1; m <= 4; m <<= 1) {
    float e0 = __shfl_xor(d0, m, 8), e1 = __shfl_xor(d1, m, 8),
          e2 = __shfl_xor(d2, m, 8), e3 = __shfl_xor(d3, m, 8),
          e4 = __shfl_xor(d4, m, 8);
    int   k0 = __shfl_xor(j0, m, 8), k1 = __shfl_xor(j1, m, 8),
          k2 = __shfl_xor(j2, m, 8), k3 = __shfl_xor(j3, m, 8),
          k4 = __shfl_xor(j4, m, 8);
    insert5(d0,d1,d2,d3,d4, j0,j1,j2,j3,j4, e0, k0);
    insert5(d0,d1,d2,d3,d4, j0,j1,j2,j3,j4, e1, k1);
    insert5(d0,d1,d2,d3,d4, j0,j1,j2,j3,j4, e2, k2);
    insert5(d0,d1,d2,d3,d4, j0,j1,j2,j3,j4, e3, k3);
    insert5(d0,d1,d2,d3,d4, j0,j1,j2,j3,j4, e4, k4);
  }
  if (ql == 0) {
    const size_t row = (size_t)b * NP + i;
    knn_idx[row*KNN+0] = b*NP + j0;
    knn_idx[row*KNN+1] = b*NP + j1;
    knn_idx[row*KNN+2] = b*NP + j2;
    knn_idx[row*KNN+3] = b*NP + j3;
    knn_idx[row*KNN+4] = b*NP + j4;
  }
}

// ------------------------------------------- EdgeConv1 layer1 (6 -> 64) + stats
__global__ __launch_bounds__(256) void ec1_l1_kernel(const float* __restrict__ pos,
    const int* __restrict__ knn_idx, const float* __restrict__ W,
    const float* __restrict__ bias, float* __restrict__ hout,
    double* __restrict__ psum, double* __restrict__ psq) {
  __shared__ float ef[64][6];
  __shared__ float Wl[6][64];
  __shared__ float bl[64];
  __shared__ double red[256];
  const int blk = blockIdx.x, t = threadIdx.x;
  const int ebase = blk * 64;
  if (t < 64) {
    int e = ebase + t;
    int ip = e / KNN;
    int jp = knn_idx[e];
    float a0 = pos[(size_t)ip*3+0], a1 = pos[(size_t)ip*3+1], a2 = pos[(size_t)ip*3+2];
    float c0 = pos[(size_t)jp*3+0], c1 = pos[(size_t)jp*3+1], c2 = pos[(size_t)jp*3+2];
    ef[t][0] = a0; ef[t][1] = a1; ef[t][2] = a2;
    ef[t][3] = c0 - a0; ef[t][4] = c1 - a1; ef[t][5] = c2 - a2;
    bl[t] = bias[t];
  }
  for (int idx = t; idx < 6*64; idx += 256) Wl[idx>>6][idx&63] = W[idx];
  __syncthreads();
  const int c = t & 63, rs = t >> 6;
  double s = 0.0, ss = 0.0;
  for (int r = rs; r < 64; r += 4) {
    float acc = bl[c];
    #pragma unroll
    for (int q = 0; q < 6; ++q) acc = fmaf(ef[r][q], Wl[q][c], acc);
    acc = fmaxf(acc, 0.0f);
    hout[(size_t)(ebase + r)*64 + c] = acc;
    s += acc; ss += (double)acc * (double)acc;
  }
  red[t] = s; __syncthreads();
  if (t < 64) psum[(size_t)blk*64 + t] = red[t] + red[t+64] + red[t+128] + red[t+192];
  __syncthreads();
  red[t] = ss; __syncthreads();
  if (t < 64) psq[(size_t)blk*64 + t] = red[t] + red[t+64] + red[t+128] + red[t+192];
}

// ------------------- BN stats -> per-channel affine (block per channel)
__global__ __launch_bounds__(256) void stats_reduce_kernel(const double* __restrict__ psum,
    const double* __restrict__ psq, int nblk, int C, double invN,
    const float* __restrict__ g, const float* __restrict__ be,
    float2* __restrict__ aff) {
  __shared__ double rs[256];
  __shared__ double rq[256];
  const int c = blockIdx.x;          // grid = C
  const int t = threadIdx.x;
  double s = 0.0, ss = 0.0;
  for (int i = t; i < nblk; i += 256) {
    s  += psum[(size_t)i*C + c];
    ss += psq [(size_t)i*C + c];
  }
  rs[t] = s; rq[t] = ss; __syncthreads();
  for (int off = 128; off > 0; off >>= 1) {
    if (t < off) { rs[t] += rs[t+off]; rq[t] += rq[t+off]; }
    __syncthreads();
  }
  if (t == 0) {
    double mean = rs[0] * invN;
    double var = rq[0] * invN - mean*mean;
    var = var < 0.0 ? 0.0 : var;
    double inv = 1.0 / sqrt(var + 1e-5);
    float a = (float)((double)g[c] * inv);
    float off2 = (float)((double)be[c] - (double)g[c] * mean * inv);
    aff[c] = make_float2(a, off2);
  }
}

// -------------------------------- EdgeConv1 layer2 (64 -> 64) + stats
__global__ __launch_bounds__(256) void ec_l64_kernel(const float* __restrict__ hin,
    const float2* __restrict__ affprev, const float* __restrict__ W,
    const float* __restrict__ bias, float* __restrict__ hout,
    double* __restrict__ psum, double* __restrict__ psq) {
  __shared__ float ein[64][68];
  __shared__ float Wl[64][64];
  __shared__ float2 affl[64];
  __shared__ float bl[64];
  __shared__ double redS[16][64];
  __shared__ double redQ[16][64];
  const int blk = blockIdx.x, t = threadIdx.x;
  const size_t ebase = (size_t)blk * 64;
  if (t < 64) { affl[t] = affprev[t]; bl[t] = bias[t]; }
  __syncthreads();
  for (int idx = t; idx < 64*64; idx += 256) {
    int r = idx >> 6, c = idx & 63;
    float2 ac = affl[c];
    ein[r][c] = fmaf(hin[ebase*64 + idx], ac.x, ac.y);
    Wl[r][c] = W[idx];
  }
  __syncthreads();
  const int c4 = t & 15, rs = t >> 4;
  const int cbase = c4 * 4;
  const int rbase = rs * 4;
  float acc[4][4];
  #pragma unroll
  for (int ii = 0; ii < 4; ++ii) {
    #pragma unroll
    for (int jj = 0; jj < 4; ++jj) acc[ii][jj] = bl[cbase + jj];
  }
  for (int cin = 0; cin < 64; cin += 4) {
    float4 fi[4];
    #pragma unroll
    for (int ii = 0; ii < 4; ++ii) fi[ii] = *(const float4*)&ein[rbase+ii][cin];
    #pragma unroll
    for (int q = 0; q < 4; ++q) {
      float4 wv = *(const float4*)&Wl[cin+q][cbase];
      #pragma unroll
      for (int ii = 0; ii < 4; ++ii) {
        float f = f4c(fi[ii], q);
        acc[ii][0] = fmaf(f, wv.x, acc[ii][0]);
        acc[ii][1] = fmaf(f, wv.y, acc[ii][1]);
        acc[ii][2] = fmaf(f, wv.z, acc[ii][2]);
        acc[ii][3] = fmaf(f, wv.w, acc[ii][3]);
      }
    }
  }
  double s[4] = {0,0,0,0}, ss[4] = {0,0,0,0};
  #pragma unroll
  for (int ii = 0; ii < 4; ++ii) {
    float4 h;
    h.x = fmaxf(acc[ii][0], 0.f); h.y = fmaxf(acc[ii][1], 0.f);
    h.z = fmaxf(acc[ii][2], 0.f); h.w = fmaxf(acc[ii][3], 0.f);
    *(float4*)&hout[(ebase + rbase + ii)*64 + cbase] = h;
    s[0]+=h.x; s[1]+=h.y; s[2]+=h.z; s[3]+=h.w;
    ss[0]+=(double)h.x*h.x; ss[1]+=(double)h.y*h.y;
    ss[2]+=(double)h.z*h.z; ss[3]+=(double)h.w*h.w;
  }
  #pragma unroll
  for (int jj = 0; jj < 4; ++jj) { redS[rs][cbase+jj] = s[jj]; redQ[rs][cbase+jj] = ss[jj]; }
  __syncthreads();
  if (t < 64) {
    double a = 0, bq = 0;
    #pragma unroll
    for (int r = 0; r < 16; ++r) { a += redS[r][t]; bq += redQ[r][t]; }
    psum[(size_t)blk*64 + t] = a;
    psq[(size_t)blk*64 + t] = bq;
  }
}

// -------- EdgeConv1 layer3 (64 -> 64) FUSED with k-max/min (R21)
// 80 edges = 16 points per block; thread row-tile of 5 rows == one point's
// k-neighborhood -> h stays in registers; write per-point hmax/hmin only.
__global__ __launch_bounds__(256) void ec_l64_last_kernel(const float* __restrict__ hin,
    const float2* __restrict__ affprev, const float* __restrict__ W,
    const float* __restrict__ bias, float* __restrict__ hmax, float* __restrict__ hmin,
    double* __restrict__ psum, double* __restrict__ psq) {
  __shared__ float ein[80][68];     // 21.76 KB
  __shared__ float Wl[64][64];      // 16 KB
  __shared__ float2 affl[64];
  __shared__ float bl[64];
  double (*redS)[64] = (double (*)[64])(&ein[0][0]);                  // aliases ein
  double (*redQ)[64] = (double (*)[64])((char*)&ein[0][0] + 8192);    // after GEMM
  const int blk = blockIdx.x, t = threadIdx.x;   // grid = NPT/16
  const size_t ebase = (size_t)blk * 80;
  if (t < 64) { affl[t] = affprev[t]; bl[t] = bias[t]; }
  __syncthreads();
  for (int idx = t; idx < 80*64; idx += 256) {
    int r = idx >> 6, c = idx & 63;
    float2 ac = affl[c];
    ein[r][c] = fmaf(hin[ebase*64 + idx], ac.x, ac.y);
  }
  for (int idx = t; idx < 64*64; idx += 256) Wl[idx>>6][idx&63] = W[idx];
  __syncthreads();
  const int c4 = t & 15, rs = t >> 4;    // rs = point index within block
  const int cbase = c4 * 4;
  const int rbase = rs * 5;              // 5 edges of point rs
  float acc[5][4];
  #pragma unroll
  for (int ii = 0; ii < 5; ++ii) {
    #pragma unroll
    for (int jj = 0; jj < 4; ++jj) acc[ii][jj] = bl[cbase + jj];
  }
  for (int cin = 0; cin < 64; cin += 4) {
    float4 fi[5];
    #pragma unroll
    for (int ii = 0; ii < 5; ++ii) fi[ii] = *(const float4*)&ein[rbase+ii][cin];
    #pragma unroll
    for (int q = 0; q < 4; ++q) {
      float4 wv = *(const float4*)&Wl[cin+q][cbase];
      #pragma unroll
      for (int ii = 0; ii < 5; ++ii) {
        float f = f4c(fi[ii], q);
        acc[ii][0] = fmaf(f, wv.x, acc[ii][0]);
        acc[ii][1] = fmaf(f, wv.y, acc[ii][1]);
        acc[ii][2] = fmaf(f, wv.z, acc[ii][2]);
        acc[ii][3] = fmaf(f, wv.w, acc[ii][3]);
      }
    }
  }
  // ReLU + in-register k-max/min + stats (h never leaves registers)
  float4 mx = make_float4(-FINF,-FINF,-FINF,-FINF);
  float4 mn = make_float4(FINF,FINF,FINF,FINF);
  double s[4] = {0,0,0,0}, ss[4] = {0,0,0,0};
  #pragma unroll
  for (int ii = 0; ii < 5; ++ii) {
    float4 h;
    h.x = fmaxf(acc[ii][0], 0.f); h.y = fmaxf(acc[ii][1], 0.f);
    h.z = fmaxf(acc[ii][2], 0.f); h.w = fmaxf(acc[ii][3], 0.f);
    mx.x = fmaxf(mx.x, h.x); mn.x = fminf(mn.x, h.x);
    mx.y = fmaxf(mx.y, h.y); mn.y = fminf(mn.y, h.y);
    mx.z = fmaxf(mx.z, h.z); mn.z = fminf(mn.z, h.z);
    mx.w = fmaxf(mx.w, h.w); mn.w = fminf(mn.w, h.w);
    s[0]+=h.x; s[1]+=h.y; s[2]+=h.z; s[3]+=h.w;
    ss[0]+=(double)h.x*h.x; ss[1]+=(double)h.y*h.y;
    ss[2]+=(double)h.z*h.z; ss[3]+=(double)h.w*h.w;
  }
  *(float4*)&hmax[((size_t)blk*16 + rs)*64 + cbase] = mx;
  *(float4*)&hmin[((size_t)blk*16 + rs)*64 + cbase] = mn;
  __syncthreads();   // all ein GEMM reads done; redS/redQ alias ein
  #pragma unroll
  for (int jj = 0; jj < 4; ++jj) { redS[rs][cbase+jj] = s[jj]; redQ[rs][cbase+jj] = ss[jj]; }
  __syncthreads();
  if (t < 64) {
    double a = 0, bq = 0;
    #pragma unroll
    for (int r = 0; r < 16; ++r) { a += redS[r][t]; bq += redQ[r][t]; }
    psum[(size_t)blk*64 + t] = a;
    psq[(size_t)blk*64 + t] = bq;
  }
}

// -------- x1 finalize (R21): affine-select + bf16 hi/lo split + |x1|^2,
// fused into ONE pass over hmax/hmin. sq order = ascending-c fmaf (exact).
__global__ __launch_bounds__(256) void x1c_kernel(const float* __restrict__ hmax,
    const float* __restrict__ hmin, const float2* __restrict__ aff,
    float* __restrict__ x1, ushort* __restrict__ x1hi, ushort* __restrict__ x1lo,
    float* __restrict__ sqg) {
  __shared__ float xs[16][65];
  const int blk = blockIdx.x, t = threadIdx.x;  // grid = NPT/16
  const size_t base = (size_t)blk * 16 * 64;
  const int o = t * 4;           // 1024 elements, 4/thread
  const int c4 = o & 63;
  float4 vmx = *(const float4*)&hmax[base + o];
  float4 vmn = *(const float4*)&hmin[base + o];
  float2 a0 = aff[c4+0], a1 = aff[c4+1], a2 = aff[c4+2], a3 = aff[c4+3];
  float4 xv;
  xv.x = (a0.x >= 0.f) ? fmaf(a0.x, vmx.x, a0.y) : fmaf(a0.x, vmn.x, a0.y);
  xv.y = (a1.x >= 0.f) ? fmaf(a1.x, vmx.y, a1.y) : fmaf(a1.x, vmn.y, a1.y);
  xv.z = (a2.x >= 0.f) ? fmaf(a2.x, vmx.z, a2.y) : fmaf(a2.x, vmn.z, a2.y);
  xv.w = (a3.x >= 0.f) ? fmaf(a3.x, vmx.w, a3.y) : fmaf(a3.x, vmn.w, a3.y);
  *(float4*)&x1[base + o] = xv;
  ushort4 h, lo;
  h.x = f2bf(xv.x); lo.x = f2bf(xv.x - bf2f(h.x));
  h.y = f2bf(xv.y); lo.y = f2bf(xv.y - bf2f(h.y));
  h.z = f2bf(xv.z); lo.z = f2bf(xv.z - bf2f(h.z));
  h.w = f2bf(xv.w); lo.w = f2bf(xv.w - bf2f(h.w));
  *(ushort4*)&x1hi[base + o] = h;
  *(ushort4*)&x1lo[base + o] = lo;
  const int r = o >> 6;
  xs[r][c4+0] = xv.x; xs[r][c4+1] = xv.y; xs[r][c4+2] = xv.z; xs[r][c4+3] = xv.w;
  __syncthreads();
  if (t < 16) {
    float s = 0.f;
    #pragma unroll
    for (int c = 0; c < 64; ++c) s = fmaf(xs[t][c], xs[t][c], s);
    sqg[(size_t)blk*16 + t] = s;
  }
}

// ---------------------------------------------------------------- knn (64-d)
// R18 form (best measured): xi/xj in LDS, half-split scan, 36.9KB.
__global__ __launch_bounds__(256) void knn2_kernel(const ushort* __restrict__ x1hi,
    const ushort* __restrict__ x1lo, const float* __restrict__ sqg,
    float* __restrict__ kpd, int* __restrict__ kpj) {
  __shared__ __align__(16) char smem[36864];
  ushort* xihi = (ushort*)smem;                 // [64][72]
  ushort* xilo = (ushort*)(smem + 9216);        // [64][72]
  ushort* xjhi = (ushort*)(smem + 18432);       // [64][72]
  ushort* xjlo = (ushort*)(smem + 27648);       // [64][72]
  float*  dist = (float*)(smem + 18432);        // [64][68], aliases xj after MFMA
  const int b = blockIdx.x >> 5;
  const int it = (blockIdx.x >> 1) & 15;
  const int half = blockIdx.x & 1;
  const int t = threadIdx.x;
  const int ibase = it * 64;  // within batch

  #pragma unroll
  for (int i = 0; i < 2; ++i) {
    int idx = i*256 + t;
    int r = idx >> 3, c8 = (idx & 7) * 8;
    *(bf16x8*)&xihi[r*72 + c8] = *(const bf16x8*)&x1hi[((size_t)b*NP + ibase + r)*64 + c8];
    *(bf16x8*)&xilo[r*72 + c8] = *(const bf16x8*)&x1lo[((size_t)b*NP + ibase + r)*64 + c8];
  }

  const int w = t >> 6, l = t & 63;
  const int lr = l & 15, lg = l >> 4;
  const int row = t >> 2, ql = t & 3;
  float si2[4];
  #pragma unroll
  for (int ii = 0; ii < 4; ++ii)
    si2[ii] = sqg[(size_t)b*NP + ibase + w*16 + lg*4 + ii];

  float d0=FINF,d1=FINF,d2=FINF,d3=FINF,d4=FINF;
  int j0=0x7fffffff,j1=0x7fffffff,j2=0x7fffffff,j3=0x7fffffff,j4=0x7fffffff;

  for (int jt = 0; jt < 8; ++jt) {
    const int jtg = half * 8 + jt;
    __syncthreads();
    #pragma unroll
    for (int i = 0; i < 2; ++i) {
      int idx = i*256 + t;
      int r = idx >> 3, c8 = (idx & 7) * 8;
      *(bf16x8*)&xjhi[r*72 + c8] = *(const bf16x8*)&x1hi[((size_t)b*NP + jtg*64 + r)*64 + c8];
      *(bf16x8*)&xjlo[r*72 + c8] = *(const bf16x8*)&x1lo[((size_t)b*NP + jtg*64 + r)*64 + c8];
    }
    __syncthreads();
    f32x4 acc0 = (f32x4){0.f,0.f,0.f,0.f};
    f32x4 acc1 = (f32x4){0.f,0.f,0.f,0.f};
    f32x4 acc2 = (f32x4){0.f,0.f,0.f,0.f};
    f32x4 acc3 = (f32x4){0.f,0.f,0.f,0.f};
    #pragma unroll
    for (int ks = 0; ks < 2; ++ks) {
      const int k0 = ks * 32;
      bf16x8 ah = *(const bf16x8*)&xihi[(w*16 + lr)*72 + k0 + lg*8];
      bf16x8 al = *(const bf16x8*)&xilo[(w*16 + lr)*72 + k0 + lg*8];
      {
        bf16x8 bh = *(const bf16x8*)&xjhi[(0*16 + lr)*72 + k0 + lg*8];
        bf16x8 bl = *(const bf16x8*)&xjlo[(0*16 + lr)*72 + k0 + lg*8];
        acc0 = __builtin_amdgcn_mfma_f32_16x16x32_bf16(ah, bh, acc0, 0, 0, 0);
        acc0 = __builtin_amdgcn_mfma_f32_16x16x32_bf16(ah, bl, acc0, 0, 0, 0);
        acc0 = __builtin_amdgcn_mfma_f32_16x16x32_bf16(al, bh, acc0, 0, 0, 0);
        acc0 = __builtin_amdgcn_mfma_f32_16x16x32_bf16(al, bl, acc0, 0, 0, 0);
      }
      {
        bf16x8 bh = *(const bf16x8*)&xjhi[(1*16 + lr)*72 + k0 + lg*8];
        bf16x8 bl = *(const bf16x8*)&xjlo[(1*16 + lr)*72 + k0 + lg*8];
        acc1 = __builtin_amdgcn_mfma_f32_16x16x32_bf16(ah, bh, acc1, 0, 0, 0);
        acc1 = __builtin_amdgcn_mfma_f32_16x16x32_bf16(ah, bl, acc1, 0, 0, 0);
        acc1 = __builtin_amdgcn_mfma_f32_16x16x32_bf16(al, bh, acc1, 0, 0, 0);
        acc1 = __builtin_amdgcn_mfma_f32_16x16x32_bf16(al, bl, acc1, 0, 0, 0);
      }
      {
        bf16x8 bh = *(const bf16x8*)&xjhi[(2*16 + lr)*72 + k0 + lg*8];
        bf16x8 bl = *(const bf16x8*)&xjlo[(2*16 + lr)*72 + k0 + lg*8];
        acc2 = __builtin_amdgcn_mfma_f32_16x16x32_bf16(ah, bh, acc2, 0, 0, 0);
        acc2 = __builtin_amdgcn_mfma_f32_16x16x32_bf16(ah, bl, acc2, 0, 0, 0);
        acc2 = __builtin_amdgcn_mfma_f32_16x16x32_bf16(al, bh, acc2, 0, 0, 0);
        acc2 = __builtin_amdgcn_mfma_f32_16x16x32_bf16(al, bl, acc2, 0, 0, 0);
      }
      {
        bf16x8 bh = *(const bf16x8*)&xjhi[(3*16 + lr)*72 + k0 + lg*8];
        bf16x8 bl = *(const bf16x8*)&xjlo[(3*16 + lr)*72 + k0 + lg*8];
        acc3 = __builtin_amdgcn_mfma_f32_16x16x32_bf16(ah, bh, acc3, 0, 0, 0);
        acc3 = __builtin_amdgcn_mfma_f32_16x16x32_bf16(ah, bl, acc3, 0, 0, 0);
        acc3 = __builtin_amdgcn_mfma_f32_16x16x32_bf16(al, bh, acc3, 0, 0, 0);
        acc3 = __builtin_amdgcn_mfma_f32_16x16x32_bf16(al, bl, acc3, 0, 0, 0);
      }
    }
    float sjv0 = sqg[(size_t)b*NP + jtg*64 + 0*16 + lr];
    float sjv1 = sqg[(size_t)b*NP + jtg*64 + 1*16 + lr];
    float sjv2 = sqg[(size_t)b*NP + jtg*64 + 2*16 + lr];
    float sjv3 = sqg[(size_t)b*NP + jtg*64 + 3*16 + lr];
    __syncthreads();
    #pragma unroll
    for (int ii = 0; ii < 4; ++ii) {
      const int irow = w*16 + lg*4 + ii;
      dist[irow*68 + 0*16 + lr] = fmaf(-2.f, acc0[ii], si2[ii] + sjv0);
      dist[irow*68 + 1*16 + lr] = fmaf(-2.f, acc1[ii], si2[ii] + sjv1);
      dist[irow*68 + 2*16 + lr] = fmaf(-2.f, acc2[ii], si2[ii] + sjv2);
      dist[irow*68 + 3*16 + lr] = fmaf(-2.f, acc3[ii], si2[ii] + sjv3);
    }
    __syncthreads();
    const int jgbase = jtg*64 + ql*16;
    #pragma unroll
    for (int kk = 0; kk < 4; ++kk) {
      float4 v = *(const float4*)&dist[row*68 + ql*16 + 4*kk];
      insert5f(d0,d1,d2,d3,d4, j0,j1,j2,j3,j4, v.x, jgbase + 4*kk + 0);
      insert5f(d0,d1,d2,d3,d4, j0,j1,j2,j3,j4, v.y, jgbase + 4*kk + 1);
      insert5f(d0,d1,d2,d3,d4, j0,j1,j2,j3,j4, v.z, jgbase + 4*kk + 2);
      insert5f(d0,d1,d2,d3,d4, j0,j1,j2,j3,j4, v.w, jgbase + 4*kk + 3);
    }
  }

  #pragma unroll
  for (int m = 1; m <= 2; m <<= 1) {
    float e0 = __shfl_xor(d0, m, 4), e1 = __shfl_xor(d1, m, 4),
          e2 = __shfl_xor(d2, m, 4), e3 = __shfl_xor(d3, m, 4),
          e4 = __shfl_xor(d4, m, 4);
    int   k0 = __shfl_xor(j0, m, 4), k1 = __shfl_xor(j1, m, 4),
          k2 = __shfl_xor(j2, m, 4), k3 = __shfl_xor(j3, m, 4),
          k4 = __shfl_xor(j4, m, 4);
    insert5(d0,d1,d2,d3,d4, j0,j1,j2,j3,j4, e0, k0);
    insert5(d0,d1,d2,d3,d4, j0,j1,j2,j3,j4, e1, k1);
    insert5(d0,d1,d2,d3,d4, j0,j1,j2,j3,j4, e2, k2);
    insert5(d0,d1,d2,d3,d4, j0,j1,j2,j3,j4, e3, k3);
    insert5(d0,d1,d2,d3,d4, j0,j1,j2,j3,j4, e4, k4);
  }
  if (ql == 0) {
    const size_t orow = ((size_t)half*NPT + (size_t)b*NP + ibase + row) * KNN;
    kpd[orow+0] = d0; kpd[orow+1] = d1; kpd[orow+2] = d2; kpd[orow+3] = d3; kpd[orow+4] = d4;
    kpj[orow+0] = j0; kpj[orow+1] = j1; kpj[orow+2] = j2; kpj[orow+3] = j3; kpj[orow+4] = j4;
  }
}

// merge the two sorted half top-5 lists (exact: half0 j < half1 j)
__global__ void knn2_merge_kernel(const float* __restrict__ kpd,
    const int* __restrict__ kpj, int* __restrict__ knn_idx) {
  int r = blockIdx.x * 256 + threadIdx.x;
  if (r >= NPT) return;
  const int b = r >> 10;
  const size_t r0 = (size_t)r * KNN;
  const size_t r1 = ((size_t)NPT + r) * KNN;
  float d0 = kpd[r0+0], d1 = kpd[r0+1], d2 = kpd[r0+2], d3 = kpd[r0+3], d4 = kpd[r0+4];
  int   j0 = kpj[r0+0], j1 = kpj[r0+1], j2 = kpj[r0+2], j3 = kpj[r0+3], j4 = kpj[r0+4];
  #pragma unroll
  for (int s = 0; s < KNN; ++s) {
    insert5(d0,d1,d2,d3,d4, j0,j1,j2,j3,j4, kpd[r1+s], kpj[r1+s]);
  }
  knn_idx[r0+0] = b*NP + j0;
  knn_idx[r0+1] = b*NP + j1;
  knn_idx[r0+2] = b*NP + j2;
  knn_idx[r0+3] = b*NP + j3;
  knn_idx[r0+4] = b*NP + j4;
}

// -------- W2[128][128] f32 -> split bf16 FRAGMENT-ORDER
__global__ __launch_bounds__(256) void wt2_kernel(const float* __restrict__ W,
    ushort* __restrict__ WthiF, ushort* __restrict__ WtloF) {
  __shared__ ushort lsh[64][128];
  __shared__ ushort lsl[64][128];
  const int cbase = blockIdx.x * 64;   // grid = 2
  const int t = threadIdx.x;
  for (int idx = t; idx < 128 * 64; idx += 256) {
    int cc = idx & 63, k = idx >> 6;
    float w = W[(size_t)k * 128 + cbase + cc];
    ushort hi = f2bf(w);
    ushort lo = f2bf(w - bf2f(hi));
    lsh[cc][k] = hi; lsl[cc][k] = lo;
  }
  __syncthreads();
  const int ctl = t >> 6, lane = t & 63;
  const int lr = lane & 15, lg = lane >> 4;
  const int ctg = (cbase >> 4) + ctl;
  #pragma unroll
  for (int ks = 0; ks < 4; ++ks) {
    size_t o = ((size_t)(ctg*4 + ks)*64 + lane) * 8;
    *(bf16x8*)&WthiF[o] = *(const bf16x8*)&lsh[ctl*16 + lr][ks*32 + lg*8];
    *(bf16x8*)&WtloF[o] = *(const bf16x8*)&lsl[ctl*16 + lr][ks*32 + lg*8];
  }
}

// ------------ EdgeConv2 (128 -> 128) SPLIT bf16 MFMA + k-max/min + stats
#define EC2S 136
__global__ __launch_bounds__(256) void ec2_kernel(const float* __restrict__ x1,
    const int* __restrict__ knn_idx, const ushort* __restrict__ WthiF,
    const ushort* __restrict__ WtloF, const float* __restrict__ bias,
    float* __restrict__ x2max, float* __restrict__ x2min,
    double* __restrict__ psum, double* __restrict__ psq) {
  __shared__ __align__(16) char smem[2 * 40 * EC2S * 2];  // 21.76 KB
  ushort* Ahi = (ushort*)smem;                       // 40*EC2S
  ushort* Alo = (ushort*)(smem + 40 * EC2S * 2);     // 40*EC2S
  float (*outs)[132] = (float (*)[132])smem;         // [40][132] aliases after GEMM
  double (*redS)[128] = (double (*)[128])smem;              // aliases after epilogue
  double (*redQ)[128] = (double (*)[128])(smem + 4*128*8);  // 8 KB total
  const int blk = blockIdx.x, t = threadIdx.x;       // grid = NPT/8
  const int pbase = blk * 8;
  // staging: 40 rows x 32 float4-groups
  for (int idx = t; idx < 40 * 32; idx += 256) {
    int r = idx >> 5, c4 = (idx & 31) * 4;
    int p = pbase + r / KNN;
    int kk = r % KNN;
    float4 v;
    if (c4 < 64) {
      v = *(const float4*)&x1[(size_t)p * 64 + c4];
    } else {
      int cc = c4 - 64;
      int j = knn_idx[(size_t)p * KNN + kk];
      float4 vj = *(const float4*)&x1[(size_t)j * 64 + cc];
      float4 vp = *(const float4*)&x1[(size_t)p * 64 + cc];
      v = make_float4(vj.x - vp.x, vj.y - vp.y, vj.z - vp.z, vj.w - vp.w);
    }
    ushort4 h, lo;
    h.x = f2bf(v.x); lo.x = f2bf(v.x - bf2f(h.x));
    h.y = f2bf(v.y); lo.y = f2bf(v.y - bf2f(h.y));
    h.z = f2bf(v.z); lo.z = f2bf(v.z - bf2f(h.z));
    h.w = f2bf(v.w); lo.w = f2bf(v.w - bf2f(h.w));
    *(ushort4*)&Ahi[r * EC2S + c4] = h;
    *(ushort4*)&Alo[r * EC2S + c4] = lo;
  }
  __syncthreads();
  const int l = t & 63, w = t >> 6;
  const int lr = l & 15, lg = l >> 4;
  f32x4 acc[3][2];
  #pragma unroll
  for (int rt = 0; rt < 3; ++rt) {
    acc[rt][0] = (f32x4){0.f,0.f,0.f,0.f};
    acc[rt][1] = (f32x4){0.f,0.f,0.f,0.f};
  }
  #pragma unroll
  for (int ks = 0; ks < 4; ++ks) {
    const int k0 = ks * 32;
    bf16x8 bh0 = *(const bf16x8*)&WthiF[((size_t)((2*w  )*4 + ks)*64 + l)*8];
    bf16x8 bh1 = *(const bf16x8*)&WthiF[((size_t)((2*w+1)*4 + ks)*64 + l)*8];
    bf16x8 bl0 = *(const bf16x8*)&WtloF[((size_t)((2*w  )*4 + ks)*64 + l)*8];
    bf16x8 bl1 = *(const bf16x8*)&WtloF[((size_t)((2*w+1)*4 + ks)*64 + l)*8];
    #pragma unroll
    for (int rt = 0; rt < 3; ++rt) {
      int ar = rt*16 + lr;
      int arc = ar < 40 ? ar : 39;   // clamp pad reads in-bounds (values unused)
      bf16x8 ah = *(const bf16x8*)&Ahi[arc * EC2S + k0 + lg*8];
      bf16x8 al = *(const bf16x8*)&Alo[arc * EC2S + k0 + lg*8];
      acc[rt][0] = __builtin_amdgcn_mfma_f32_16x16x32_bf16(ah, bh0, acc[rt][0], 0, 0, 0);
      acc[rt][0] = __builtin_amdgcn_mfma_f32_16x16x32_bf16(ah, bl0, acc[rt][0], 0, 0, 0);
      acc[rt][0] = __builtin_amdgcn_mfma_f32_16x16x32_bf16(al, bh0, acc[rt][0], 0, 0, 0);
      acc[rt][1] = __builtin_amdgcn_mfma_f32_16x16x32_bf16(ah, bh1, acc[rt][1], 0, 0, 0);
      acc[rt][1] = __builtin_amdgcn_mfma_f32_16x16x32_bf16(ah, bl1, acc[rt][1], 0, 0, 0);
      acc[rt][1] = __builtin_amdgcn_mfma_f32_16x16x32_bf16(al, bh1, acc[rt][1], 0, 0, 0);
    }
  }
  __syncthreads();   // all Ahi/Alo reads done before outs aliases them
  {
    const float bv0 = bias[w*32 + lr];
    const float bv1 = bias[w*32 + 16 + lr];
    #pragma unroll
    for (int rt = 0; rt < 3; ++rt) {
      #pragma unroll
      for (int i = 0; i < 4; ++i) {
        int e = rt*16 + lg*4 + i;
        if (e < 40) {
          outs[e][w*32 + lr]      = fmaxf(acc[rt][0][i] + bv0, 0.f);
          outs[e][w*32 + 16 + lr] = fmaxf(acc[rt][1][i] + bv1, 0.f);
        }
      }
    }
  }
  __syncthreads();
  // per-point k-max/min; per-thread stats held in regs
  double s4[4] = {0,0,0,0}, q4[4] = {0,0,0,0};
  {
    const int p = t >> 5;             // 8 points, 32 threads each
    const int cs = (t & 31) * 4;      // 4 cols per thread
    float4 mx = make_float4(-FINF,-FINF,-FINF,-FINF);
    float4 mn = make_float4(FINF,FINF,FINF,FINF);
    #pragma unroll
    for (int kk = 0; kk < KNN; ++kk) {
      float4 va = *(const float4*)&outs[p*KNN + kk][cs];
      mx.x = fmaxf(mx.x, va.x); mn.x = fminf(mn.x, va.x); s4[0] += va.x; q4[0] += (double)va.x*va.x;
      mx.y = fmaxf(mx.y, va.y); mn.y = fminf(mn.y, va.y); s4[1] += va.y; q4[1] += (double)va.y*va.y;
      mx.z = fmaxf(mx.z, va.z); mn.z = fminf(mn.z, va.z); s4[2] += va.z; q4[2] += (double)va.z*va.z;
      mx.w = fmaxf(mx.w, va.w); mn.w = fminf(mn.w, va.w); s4[3] += va.w; q4[3] += (double)va.w*va.w;
    }
    *(float4*)&x2max[((size_t)pbase + p)*128 + cs] = mx;
    *(float4*)&x2min[((size_t)pbase + p)*128 + cs] = mn;
    // reduce across the 2 points of this wave (lanes l and l^32)
    #pragma unroll
    for (int cc = 0; cc < 4; ++cc) {
      s4[cc] += __shfl_xor(s4[cc], 32);
      q4[cc] += __shfl_xor(q4[cc], 32);
    }
  }
  __syncthreads();   // all outs reads done; redS/redQ alias smem
  {
    const int cs = (t & 31) * 4;
    if ((t & 63) < 32) {
      #pragma unroll
      for (int cc = 0; cc < 4; ++cc) {
        redS[t >> 6][cs + cc] = s4[cc];
        redQ[t >> 6][cs + cc] = q4[cc];
      }
    }
  }
  __syncthreads();
  if (t < 128) {
    double a = redS[0][t] + redS[1][t] + redS[2][t] + redS[3][t];
    double q = redQ[0][t] + redQ[1][t] + redQ[2][t] + redQ[3][t];
    psum[(size_t)blk*128 + t] = a;
    psq [(size_t)blk*128 + t] = q;
  }
}

// ------- x2 = BN-affine(x2max/x2min) -> bf16, ONCE
__global__ void x2c_kernel(const float* __restrict__ x2max,
    const float* __restrict__ x2min, const float2* __restrict__ aff2,
    ushort* __restrict__ x2bf) {
  int idx = blockIdx.x * 256 + threadIdx.x;   // grid = NPT*128/1024
  int o = idx * 4;
  int c4 = o & 127;
  float4 vmx = *(const float4*)&x2max[o];
  float4 vmn = *(const float4*)&x2min[o];
  float2 a0 = aff2[c4+0], a1 = aff2[c4+1], a2 = aff2[c4+2], a3 = aff2[c4+3];
  ushort4 hv;
  hv.x = f2bf((a0.x >= 0.f) ? fmaf(a0.x, vmx.x, a0.y) : fmaf(a0.x, vmn.x, a0.y));
  hv.y = f2bf((a1.x >= 0.f) ? fmaf(a1.x, vmx.y, a1.y) : fmaf(a1.x, vmn.y, a1.y));
  hv.z = f2bf((a2.x >= 0.f) ? fmaf(a2.x, vmx.z, a2.y) : fmaf(a2.x, vmn.z, a2.y));
  hv.w = f2bf((a3.x >= 0.f) ? fmaf(a3.x, vmx.w, a3.y) : fmaf(a3.x, vmn.w, a3.y));
  *(ushort4*)&x2bf[o] = hv;
}

// ---- W[192][1024] f32 -> bf16 FRAGMENT-ORDER
__global__ __launch_bounds__(256) void wt_kernel(const float* __restrict__ W,
                                                 ushort* __restrict__ WtF) {
  __shared__ ushort ls[64][192];
  const int cbase = blockIdx.x * 64;   // grid = 16
  const int t = threadIdx.x;
  for (int idx = t; idx < 192 * 64; idx += 256) {
    int cc = idx & 63, k = idx >> 6;
    ls[cc][k] = f2bf(W[(size_t)k * 1024 + cbase + cc]);
  }
  __syncthreads();
  const int ctl = t >> 6, lane = t & 63;
  const int lr = lane & 15, lg = lane >> 4;
  const int ctg = (cbase >> 4) + ctl;
  #pragma unroll
  for (int ks = 0; ks < 6; ++ks) {
    size_t o = ((size_t)(ctg*6 + ks)*64 + lane) * 8;
    *(bf16x8*)&WtF[o] = *(const bf16x8*)&ls[ctl*16 + lr][ks*32 + lg*8];
  }
}

// ------------- Lin1 (192 -> 1024) bf16 MFMA, fused ReLU + stats + max/min
__global__ __launch_bounds__(256) void lin1_kernel(const ushort* __restrict__ x1hi,
    const ushort* __restrict__ x2bf, const ushort* __restrict__ WtF,
    const float* __restrict__ bias, double* __restrict__ psum,
    double* __restrict__ psq, float* __restrict__ pmax, float* __restrict__ pmin) {
  __shared__ ushort As[64 * 208];   // 64 rows x 192 bf16, stride 208
  const int blk = blockIdx.x, t = threadIdx.x;
  const int brow = blk >> 1;          // 512 row tiles
  const int ch = blk & 1;             // col half (512 cols)
  const int pbase = brow * 64;
  #pragma unroll
  for (int i = 0; i < 2; ++i) {
    int idx = i*256 + t;
    int r = idx >> 3, c8 = (idx & 7) * 8;
    *(bf16x8*)&As[r*208 + c8] = *(const bf16x8*)&x1hi[((size_t)pbase + r)*64 + c8];
  }
  #pragma unroll
  for (int i = 0; i < 4; ++i) {
    int idx = i*256 + t;
    int r = idx >> 4, c8 = (idx & 15) * 8;
    *(bf16x8*)&As[r*208 + 64 + c8] = *(const bf16x8*)&x2bf[((size_t)pbase + r)*128 + c8];
  }
  __syncthreads();
  const int l = t & 63, w = t >> 6;
  const int lr = l & 15, lg = l >> 4;
  f32x4 acc[8][4];
  #pragma unroll
  for (int ct = 0; ct < 8; ++ct) {
    #pragma unroll
    for (int rf = 0; rf < 4; ++rf) acc[ct][rf] = (f32x4){0.f, 0.f, 0.f, 0.f};
  }
  #pragma unroll
  for (int ks = 0; ks < 6; ++ks) {
    const int k0 = ks * 32;
    bf16x8 a0 = *(const bf16x8*)&As[( 0 + lr) * 208 + k0 + lg * 8];
    bf16x8 a1 = *(const bf16x8*)&As[(16 + lr) * 208 + k0 + lg * 8];
    bf16x8 a2 = *(const bf16x8*)&As[(32 + lr) * 208 + k0 + lg * 8];
    bf16x8 a3 = *(const bf16x8*)&As[(48 + lr) * 208 + k0 + lg * 8];
    #pragma unroll
    for (int ct = 0; ct < 8; ++ct) {
      bf16x8 bv = *(const bf16x8*)&WtF[((size_t)((ch*32 + w*8 + ct)*6 + ks)*64 + l)*8];
      acc[ct][0] = __builtin_amdgcn_mfma_f32_16x16x32_bf16(a0, bv, acc[ct][0], 0, 0, 0);
      acc[ct][1] = __builtin_amdgcn_mfma_f32_16x16x32_bf16(a1, bv, acc[ct][1], 0, 0, 0);
      acc[ct][2] = __builtin_amdgcn_mfma_f32_16x16x32_bf16(a2, bv, acc[ct][2], 0, 0, 0);
      acc[ct][3] = __builtin_amdgcn_mfma_f32_16x16x32_bf16(a3, bv, acc[ct][3], 0, 0, 0);
    }
  }
  #pragma unroll
  for (int ct = 0; ct < 8; ++ct) {
    const int c = ch*512 + w*128 + ct * 16 + lr;
    const float bv = bias[c];
    double s = 0.0, ss = 0.0;
    float mx = -FINF, mn = FINF;
    #pragma unroll
    for (int rf = 0; rf < 4; ++rf) {
      #pragma unroll
      for (int i = 0; i < 4; ++i) {
        float h = fmaxf(acc[ct][rf][i] + bv, 0.f);
        s += (double)h;
        ss += (double)h * h;
        mx = fmaxf(mx, h);
        mn = fminf(mn, h);
      }
    }
    s  += __shfl_xor(s, 16);  ss += __shfl_xor(ss, 16);
    mx = fmaxf(mx, __shfl_xor(mx, 16)); mn = fminf(mn, __shfl_xor(mn, 16));
    s  += __shfl_xor(s, 32);  ss += __shfl_xor(ss, 32);
    mx = fmaxf(mx, __shfl_xor(mx, 32)); mn = fminf(mn, __shfl_xor(mn, 32));
    if (lg == 0) {
      psum[(size_t)brow * 1024 + c] = s;
      psq [(size_t)brow * 1024 + c] = ss;
      pmax[(size_t)brow * 1024 + c] = mx;
      pmin[(size_t)brow * 1024 + c] = mn;
    }
  }
}

// ----------------- lin1 BN+maxpool finalize (block per channel; 512 partials)
__global__ __launch_bounds__(256) void lin1_fin_kernel(const double* __restrict__ psum,
    const double* __restrict__ psq, const float* __restrict__ pmax,
    const float* __restrict__ pmin, const float* __restrict__ g,
    const float* __restrict__ be, float* __restrict__ y) {
  __shared__ double rs[256];
  __shared__ double rq[256];
  __shared__ float smx[32][8];
  __shared__ float smn[32][8];
  __shared__ float sa[2];
  const int c = blockIdx.x;          // grid = 1024
  const int t = threadIdx.x;
  double s = 0.0, ss = 0.0;
  for (int i = t; i < 512; i += 256) {
    s  += psum[(size_t)i*1024 + c];
    ss += psq [(size_t)i*1024 + c];
  }
  rs[t] = s; rq[t] = ss; __syncthreads();
  for (int off = 128; off > 0; off >>= 1) {
    if (t < off) { rs[t] += rs[t+off]; rq[t] += rq[t+off]; }
    __syncthreads();
  }
  if (t == 0) {
    double mean = rs[0] / 32768.0;
    double var = rq[0] / 32768.0 - mean*mean;
    var = var < 0.0 ? 0.0 : var;
    double inv = 1.0 / sqrt(var + 1e-5);
    sa[0] = (float)((double)g[c] * inv);
    sa[1] = (float)((double)be[c] - (double)g[c]*mean*inv);
  }
  {
    int b = t >> 3, q = t & 7;
    float mxv = -FINF, mnv = FINF;
    #pragma unroll
    for (int k = 0; k < 2; ++k) {
      int i = b*16 + q*2 + k;
      mxv = fmaxf(mxv, pmax[(size_t)i*1024 + c]);
      mnv = fminf(mnv, pmin[(size_t)i*1024 + c]);
    }
    smx[b][q] = mxv;
    smn[b][q] = mnv;
  }
  __syncthreads();
  if (t < 32) {
    float mxv = -FINF, mnv = FINF;
    #pragma unroll
    for (int q = 0; q < 8; ++q) { mxv = fmaxf(mxv, smx[t][q]); mnv = fminf(mnv, smn[t][q]); }
    float a = sa[0], off2 = sa[1];
    y[(size_t)t*1024 + c] = (a >= 0.f) ? fmaf(a, mxv, off2) : fmaf(a, mnv, off2);
  }
}

// ---------------------------------------------------------------- head MLP
__global__ __launch_bounds__(256) void head1_kernel(const float* __restrict__ y,
    const float* __restrict__ W, const float* __restrict__ bias, float* __restrict__ h5) {
  __shared__ float yr[1024];
  __shared__ float part[256];
  const int r = blockIdx.x >> 2;
  const int cseg = (blockIdx.x & 3) * 128;
  const int t = threadIdx.x;
  for (int i = t; i < 1024; i += 256) yr[i] = y[(size_t)r*1024 + i];
  __syncthreads();
  const int c = cseg + (t & 127);
  const int kh = t >> 7;
  const int kbase = kh * 512;
  float a0 = 0.f, a1 = 0.f, a2 = 0.f, a3 = 0.f;
  for (int cin = 0; cin < 512; cin += 4) {
    a0 = fmaf(yr[kbase+cin+0], W[(size_t)(kbase+cin+0)*512 + c], a0);
    a1 = fmaf(yr[kbase+cin+1], W[(size_t)(kbase+cin+1)*512 + c], a1);
    a2 = fmaf(yr[kbase+cin+2], W[(size_t)(kbase+cin+2)*512 + c], a2);
    a3 = fmaf(yr[kbase+cin+3], W[(size_t)(kbase+cin+3)*512 + c], a3);
  }
  part[t] = ((a0 + a1) + (a2 + a3));
  __syncthreads();
  if (t < 128) {
    float acc = bias[c] + part[t] + part[t + 128];
    h5[(size_t)r*512 + c] = fmaxf(acc, 0.f);
  }
}

__global__ void bn_rows_kernel(const float* __restrict__ h, int C, int R,
    const float* __restrict__ g, const float* __restrict__ be, float2* __restrict__ aff) {
  int c = blockIdx.x*256 + threadIdx.x;
  if (c >= C) return;
  double s = 0, ss = 0;
  for (int r = 0; r < R; ++r) {
    double v = (double)h[(size_t)r*C + c];
    s += v; ss += v*v;
  }
  double mean = s / (double)R;
  double var = ss / (double)R - mean*mean;
  var = var < 0.0 ? 0.0 : var;
  double inv = 1.0 / sqrt(var + 1e-5);
  float a = (float)((double)g[c] * inv);
  float off = (float)((double)be[c] - (double)g[c]*mean*inv);
  aff[c] = make_float2(a, off);
}

__global__ __launch_bounds__(256) void head2_kernel(const float* __restrict__ h5,
    const float2* __restrict__ aff, const float* __restrict__ W,
    const float* __restrict__ bias, float* __restrict__ h6) {
  __shared__ float hr[512];
  const int r = blockIdx.x;            // grid = 32
  const int t = threadIdx.x;
  for (int i = t; i < 512; i += 256) {
    float2 a = aff[i];
    hr[i] = fmaf(a.x, h5[(size_t)r*512 + i], a.y);
  }
  __syncthreads();
  const int c = t;
  float a0 = 0.f, a1 = 0.f, a2 = 0.f, a3 = 0.f;
  for (int cin = 0; cin < 512; cin += 4) {
    a0 = fmaf(hr[cin+0], W[(size_t)(cin+0)*256 + c], a0);
    a1 = fmaf(hr[cin+1], W[(size_t)(cin+1)*256 + c], a1);
    a2 = fmaf(hr[cin+2], W[(size_t)(cin+2)*256 + c], a2);
    a3 = fmaf(hr[cin+3], W[(size_t)(cin+3)*256 + c], a3);
  }
  float acc = bias[c] + ((a0 + a1) + (a2 + a3));
  h6[(size_t)r*256 + c] = fmaxf(acc, 0.f);
}

__global__ void head3_kernel(const float* __restrict__ h6, const float2* __restrict__ aff,
    const float* __restrict__ W, const float* __restrict__ bias, float* __restrict__ out) {
  int t = threadIdx.x;
  if (t >= 64) return;
  int r = t >> 1, c = t & 1;
  float acc = bias[c];
  for (int cin = 0; cin < 256; ++cin) {
    float2 a = aff[cin];
    acc = fmaf(fmaf(a.x, h6[(size_t)r*256 + cin], a.y), W[(size_t)cin*2 + c], acc);
  }
  out[(size_t)r*2 + c] = acc;
}

// ------------------------------------------------------------------ launcher
extern "C" void kernel_launch(void* const* d_in, const int* in_sizes, int n_in,
                              void* d_out, int out_size, void* d_ws, size_t ws_size,
                              hipStream_t stream) {
  (void)in_sizes; (void)n_in; (void)out_size; (void)ws_size;
  const float* pos    = (const float*)d_in[0];
  const float* c1_w1  = (const float*)d_in[2];
  const float* c1_b1  = (const float*)d_in[3];
  const float* c1_g1  = (const float*)d_in[4];
  const float* c1_be1 = (const float*)d_in[5];
  const float* c1_w2  = (const float*)d_in[6];
  const float* c1_b2  = (const float*)d_in[7];
  const float* c1_g2  = (const float*)d_in[8];
  const float* c1_be2 = (const float*)d_in[9];
  const float* c1_w3  = (const float*)d_in[10];
  const float* c1_b3  = (const float*)d_in[11];
  const float* c1_g3  = (const float*)d_in[12];
  const float* c1_be3 = (const float*)d_in[13];
  const float* c2_w1  = (const float*)d_in[14];
  const float* c2_b1  = (const float*)d_in[15];
  const float* c2_g1  = (const float*)d_in[16];
  const float* c2_be1 = (const float*)d_in[17];
  const float* l1_w   = (const float*)d_in[18];
  const float* l1_b   = (const float*)d_in[19];
  const float* l1_g   = (const float*)d_in[20];
  const float* l1_be  = (const float*)d_in[21];
  const float* m1_w   = (const float*)d_in[22];
  const float* m1_b   = (const float*)d_in[23];
  const float* m1_g   = (const float*)d_in[24];
  const float* m1_be  = (const float*)d_in[25];
  const float* m2_w   = (const float*)d_in[26];
  const float* m2_b   = (const float*)d_in[27];
  const float* m2_g   = (const float*)d_in[28];
  const float* m2_be  = (const float*)d_in[29];
  const float* m3_w   = (const float*)d_in[30];
  const float* m3_b   = (const float*)d_in[31];

  char* ws = (char*)d_ws;
  size_t off = 0;
  auto alloc = [&](size_t bytes) -> void* {
    void* p = ws + off;
    off += (bytes + 255) & ~(size_t)255;
    return p;
  };
  int*    idx1 = (int*)alloc((size_t)NE * 4);
  int*    idx2 = (int*)alloc((size_t)NE * 4);
  float*  x1   = (float*)alloc((size_t)NPT * 64 * 4);
  float*  hA   = (float*)alloc((size_t)NE * 64 * 4);
  float*  hB   = (float*)alloc((size_t)NE * 64 * 4);
  double* psum = (double*)alloc((size_t)1048576 * 8);
  double* psq  = (double*)alloc((size_t)1048576 * 8);
  float*  pmax = (float*)alloc((size_t)1048576 * 4);
  float*  pmin = (float*)alloc((size_t)1048576 * 4);
  float2* affA = (float2*)alloc(64 * 8);
  float2* affB = (float2*)alloc(64 * 8);
  float2* affC = (float2*)alloc(64 * 8);
  float2* aff2 = (float2*)alloc(128 * 8);
  float2* affM1 = (float2*)alloc(512 * 8);
  float2* affM2 = (float2*)alloc(256 * 8);
  float*  y    = (float*)alloc((size_t)NB * 1024 * 4);
  float*  h5   = (float*)alloc((size_t)NB * 512 * 4);
  float*  h6   = (float*)alloc((size_t)NB * 256 * 4);
  ushort* WtF  = (ushort*)alloc((size_t)1024 * 192 * 2);
  ushort* Wt2hiF = (ushort*)alloc((size_t)128 * 128 * 2);
  ushort* Wt2loF = (ushort*)alloc((size_t)128 * 128 * 2);
  float*  sqg  = (float*)alloc((size_t)NPT * 4);
  ushort* x1hi = (ushort*)alloc((size_t)NPT * 64 * 2);
  ushort* x1lo = (ushort*)alloc((size_t)NPT * 64 * 2);
  ushort* x2bf = (ushort*)alloc((size_t)NPT * 128 * 2);
  float*  kpd  = (float*)alloc((size_t)2 * NPT * KNN * 4);
  int*    kpj  = (int*)alloc((size_t)2 * NPT * KNN * 4);
  // hmax/hmin live in hA (free after layer2); same region later = x2max/x2min
  float* hmax = hA;
  float* hmin = hA + (size_t)NPT * 64;
  float* x2max = hA;
  float* x2min = hA + (size_t)NPT * 128;

  // 0. weight conversions (fragment-order)
  wt_kernel<<<dim3(16), dim3(256), 0, stream>>>(l1_w, WtF);
  wt2_kernel<<<dim3(2), dim3(256), 0, stream>>>(c2_w1, Wt2hiF, Wt2loF);
  // 1. knn on positions
  knn1_kernel<<<dim3(NB*32), dim3(256), 0, stream>>>(pos, idx1);
  // 2. EdgeConv1 layer1
  ec1_l1_kernel<<<dim3(NE/64), dim3(256), 0, stream>>>(pos, idx1, c1_w1, c1_b1, hA, psum, psq);
  stats_reduce_kernel<<<dim3(64), dim3(256), 0, stream>>>(psum, psq, NE/64, 64, 1.0/NE, c1_g1, c1_be1, affA);
  // 3. layer2
  ec_l64_kernel<<<dim3(NE/64), dim3(256), 0, stream>>>(hA, affA, c1_w2, c1_b2, hB, psum, psq);
  stats_reduce_kernel<<<dim3(64), dim3(256), 0, stream>>>(psum, psq, NE/64, 64, 1.0/NE, c1_g2, c1_be2, affB);
  // 4. layer3 FUSED with k-max/min (R21); hmax/hmin overwrite hA (free now)
  ec_l64_last_kernel<<<dim3(NPT/16), dim3(256), 0, stream>>>(hB, affB, c1_w3, c1_b3, hmax, hmin, psum, psq);
  stats_reduce_kernel<<<dim3(64), dim3(256), 0, stream>>>(psum, psq, NPT/16, 64, 1.0/NE, c1_g3, c1_be3, affC);
  // 5. x1 finalize: affine + bf16 split + |x1|^2, one pass (R21)
  x1c_kernel<<<dim3(NPT/16), dim3(256), 0, stream>>>(hmax, hmin, affC, x1, x1hi, x1lo, sqg);
  // 6. knn on features (R18 form)
  knn2_kernel<<<dim3(NB*32), dim3(256), 0, stream>>>(x1hi, x1lo, sqg, kpd, kpj);
  knn2_merge_kernel<<<dim3(NPT/256), dim3(256), 0, stream>>>(kpd, kpj, idx2);
  // 7. EdgeConv2 split-bf16 MFMA (8 pts/block, block-level stats)
  ec2_kernel<<<dim3(NPT/8), dim3(256), 0, stream>>>(x1, idx2, Wt2hiF, Wt2loF, c2_b1, x2max, x2min, psum, psq);
  stats_reduce_kernel<<<dim3(128), dim3(256), 0, stream>>>(psum, psq, NPT/8, 128, 1.0/NE, c2_g1, c2_be1, aff2);
  // 7b. x2 BN+bf16 conversion
  x2c_kernel<<<dim3(NPT*128/1024), dim3(256), 0, stream>>>(x2max, x2min, aff2, x2bf);
  // 8. Lin1 bf16-MFMA fused (pure-copy staging)
  lin1_kernel<<<dim3(1024), dim3(256), 0, stream>>>(x1hi, x2bf, WtF, l1_b, psum, psq, pmax, pmin);
  lin1_fin_kernel<<<dim3(1024), dim3(256), 0, stream>>>(psum, psq, pmax, pmin, l1_g, l1_be, y);
  // 9. head
  head1_kernel<<<dim3(128), dim3(256), 0, stream>>>(y, m1_w, m1_b, h5);
  bn_rows_kernel<<<dim3(2), dim3(256), 0, stream>>>(h5, 512, NB, m1_g, m1_be, affM1);
  head2_kernel<<<dim3(32), dim3(256), 0, stream>>>(h5, affM1, m2_w, m2_b, h6);
  bn_rows_kernel<<<dim3(1), dim3(256), 0, stream>>>(h6, 256, NB, m2_g, m2_be, affM2);
  head3_kernel<<<dim3(1), dim3(64), 0, stream>>>(h6, affM2, m3_w, m3_b, (float*)d_out);
}